// Round 1
// baseline (345.884 us; speedup 1.0000x reference)
//
#include <hip/hip_runtime.h>
#include <hip/hip_bf16.h>
#include <math.h>

typedef __bf16 bf16_t;
typedef __bf16 bf16x8 __attribute__((ext_vector_type(8)));
typedef __bf16 bf16x4 __attribute__((ext_vector_type(4)));
typedef float f32x4 __attribute__((ext_vector_type(4)));

#define B_DIM 1024
#define D_DIM 1024
#define H_DIM 2048
#define E_DIM 8
#define M_DIM 2048

// ---------------- transpose + f32->bf16 convert: in [R][C] f32 -> out [C][R] bf16 ----------------
__global__ __launch_bounds__(256) void transpose_cvt_kernel(
    const float* __restrict__ in, bf16_t* __restrict__ out, int R, int C) {
  __shared__ float tile[64][65];
  const size_t matsz = (size_t)R * C;
  const float* inp = in + matsz * blockIdx.z;
  bf16_t* outp = out + matsz * blockIdx.z;
  int c0 = blockIdx.x * 64, r0 = blockIdx.y * 64;
  int tx = threadIdx.x & 63, ty = threadIdx.x >> 6;
#pragma unroll
  for (int i = 0; i < 16; ++i) {
    int r = ty + i * 4;
    tile[r][tx] = inp[(size_t)(r0 + r) * C + c0 + tx];
  }
  __syncthreads();
#pragma unroll
  for (int i = 0; i < 16; ++i) {
    int c = ty + i * 4;
    outp[(size_t)(c0 + c) * R + r0 + tx] = (bf16_t)tile[tx][c];
  }
}

// ---------------- gate: softmax(x @ gate_w) -> gate [B][E] f32 ----------------
__global__ __launch_bounds__(256) void gate_kernel(
    const float* __restrict__ x, const float* __restrict__ gw, float* __restrict__ gate) {
  __shared__ float red[256][8];
  int b = blockIdx.x, t = threadIdx.x;
  float acc[8] = {0.f, 0.f, 0.f, 0.f, 0.f, 0.f, 0.f, 0.f};
  for (int d = t; d < D_DIM; d += 256) {
    float xv = x[(size_t)b * D_DIM + d];
#pragma unroll
    for (int e = 0; e < 8; ++e) acc[e] += xv * gw[d * 8 + e];
  }
#pragma unroll
  for (int e = 0; e < 8; ++e) red[t][e] = acc[e];
  __syncthreads();
  for (int s = 128; s > 0; s >>= 1) {
    if (t < s) {
#pragma unroll
      for (int e = 0; e < 8; ++e) red[t][e] += red[t + s][e];
    }
    __syncthreads();
  }
  if (t == 0) {
    float m = red[0][0];
#pragma unroll
    for (int e = 1; e < 8; ++e) m = fmaxf(m, red[0][e]);
    float p[8], sum = 0.f;
#pragma unroll
    for (int e = 0; e < 8; ++e) { p[e] = expf(red[0][e] - m); sum += p[e]; }
    float inv = 1.f / sum;
#pragma unroll
    for (int e = 0; e < 8; ++e) gate[b * 8 + e] = p[e] * inv;
  }
}

// ---------------- conn gate per expert: sigmoid(relu(avg@w1+b1)@w2+b2)*mask -> [E][H] f32 ----------------
__global__ __launch_bounds__(256) void conn_kernel(
    const float* __restrict__ avg, const float* __restrict__ w1, const float* __restrict__ b1,
    const float* __restrict__ w2, const float* __restrict__ b2, const float* __restrict__ mask,
    float* __restrict__ conn) {
  __shared__ float red[256 * 32];
  __shared__ float h1[32];
  int e = blockIdx.x, t = threadIdx.x;
  float acc[32];
#pragma unroll
  for (int k = 0; k < 32; ++k) acc[k] = 0.f;
  for (int h = t; h < H_DIM; h += 256) {
    float av = avg[e * H_DIM + h];
    const float* w1p = &w1[((size_t)e * H_DIM + h) * 32];
#pragma unroll
    for (int k = 0; k < 32; ++k) acc[k] += av * w1p[k];
  }
#pragma unroll
  for (int k = 0; k < 32; ++k) red[t * 32 + k] = acc[k];
  __syncthreads();
  for (int s = 128; s > 0; s >>= 1) {
    if (t < s) {
#pragma unroll
      for (int k = 0; k < 32; ++k) red[t * 32 + k] += red[(t + s) * 32 + k];
    }
    __syncthreads();
  }
  if (t < 32) h1[t] = fmaxf(red[t] + b1[e * 32 + t], 0.f);
  __syncthreads();
  for (int h = t; h < H_DIM; h += 256) {
    float s = b2[e * H_DIM + h];
#pragma unroll
    for (int k = 0; k < 32; ++k) s += h1[k] * w2[((size_t)e * 32 + k) * H_DIM + h];
    conn[e * H_DIM + h] = (1.f / (1.f + expf(-s))) * mask[e * H_DIM + h];
  }
}

// ---------------- GEMM: C[64x128 tile] = A[M,K] * Bt[N,K]^T (Bt rows k-contiguous bf16) ----------------
// A_F32: A is f32 (converted on stage) else bf16. EPI 0: expert epilogue (relu/conn/gate + atomicAdd),
// EPI 1: plain f32 store.
template <int A_F32, int EPI>
__global__ __launch_bounds__(256) void gemm_kernel(
    const void* __restrict__ Av, const bf16_t* __restrict__ Bt, float* __restrict__ C,
    int K, int lda, int ldc, size_t strideB,
    const float* __restrict__ gate, const float* __restrict__ conn,
    const float* __restrict__ ebias) {
  __shared__ bf16_t As[64][72];
  __shared__ bf16_t Bs[128][72];
  const int b0 = blockIdx.x * 64;
  const int n0 = blockIdx.y * 128;
  const int e = blockIdx.z;
  const bf16_t* Bp = Bt + strideB * (size_t)e;
  const int t = threadIdx.x;
  const int lane = t & 63, wave = t >> 6;
  const int wm = wave >> 1, wn = wave & 1;
  const int lr = lane & 15, lk = (lane >> 4) * 8;

  const f32x4 zv = {0.f, 0.f, 0.f, 0.f};
  f32x4 acc[2][4];
#pragma unroll
  for (int mf = 0; mf < 2; ++mf)
#pragma unroll
    for (int nf = 0; nf < 4; ++nf) acc[mf][nf] = zv;

  const int nkt = K >> 6;
  for (int kt = 0; kt < nkt; ++kt) {
    const int k0 = kt << 6;
    if (A_F32) {
      const float* A = (const float*)Av;
      int c4 = (t & 15) * 4, r = t >> 4;
#pragma unroll
      for (int i = 0; i < 4; ++i) {
        int rr = r + 16 * i;
        float4 v = *(const float4*)&A[(size_t)(b0 + rr) * lda + k0 + c4];
        bf16x4 cv;
        cv[0] = (bf16_t)v.x; cv[1] = (bf16_t)v.y; cv[2] = (bf16_t)v.z; cv[3] = (bf16_t)v.w;
        *(bf16x4*)&As[rr][c4] = cv;
      }
    } else {
      const bf16_t* A = (const bf16_t*)Av;
      int c8 = (t & 7) * 8, r = t >> 3;
#pragma unroll
      for (int i = 0; i < 2; ++i) {
        int rr = r + 32 * i;
        *(bf16x8*)&As[rr][c8] = *(const bf16x8*)&A[(size_t)(b0 + rr) * lda + k0 + c8];
      }
    }
    {
      int c8 = (t & 7) * 8, r = t >> 3;
#pragma unroll
      for (int i = 0; i < 4; ++i) {
        int rr = r + 32 * i;
        *(bf16x8*)&Bs[rr][c8] = *(const bf16x8*)&Bp[(size_t)(n0 + rr) * K + k0 + c8];
      }
    }
    __syncthreads();
#pragma unroll
    for (int kk = 0; kk < 2; ++kk) {
      bf16x8 af[2], bfr[4];
#pragma unroll
      for (int mf = 0; mf < 2; ++mf)
        af[mf] = *(const bf16x8*)&As[wm * 32 + mf * 16 + lr][kk * 32 + lk];
#pragma unroll
      for (int nf = 0; nf < 4; ++nf)
        bfr[nf] = *(const bf16x8*)&Bs[wn * 64 + nf * 16 + lr][kk * 32 + lk];
#pragma unroll
      for (int mf = 0; mf < 2; ++mf)
#pragma unroll
        for (int nf = 0; nf < 4; ++nf)
          acc[mf][nf] = __builtin_amdgcn_mfma_f32_16x16x32_bf16(af[mf], bfr[nf], acc[mf][nf], 0, 0, 0);
    }
    __syncthreads();
  }

  const int r4 = (lane >> 4) * 4;
#pragma unroll
  for (int mf = 0; mf < 2; ++mf) {
#pragma unroll
    for (int nf = 0; nf < 4; ++nf) {
      int gcol = n0 + wn * 64 + nf * 16 + lr;
      float cm = 0.f, bb = 0.f;
      if (EPI == 0) {
        cm = conn[e * H_DIM + gcol];
        bb = ebias[e * H_DIM + gcol];
      }
#pragma unroll
      for (int j = 0; j < 4; ++j) {
        int grow = b0 + wm * 32 + mf * 16 + r4 + j;
        float v = acc[mf][nf][j];
        if (EPI == 0) {
          float g = gate[grow * E_DIM + e];
          v = (v + bb) * cm;
          v = fmaxf(v, 0.f) * g;
          atomicAdd(&C[(size_t)grow * ldc + gcol], v);
        } else {
          C[(size_t)grow * ldc + gcol] = v;
        }
      }
    }
  }
}

// ---------------- softmax over M with bias -> bf16 attn ----------------
__global__ __launch_bounds__(256) void softmax_kernel(
    const float* __restrict__ logits, const float* __restrict__ bias, bf16_t* __restrict__ attn) {
  int b = blockIdx.x, t = threadIdx.x;
  int lane = t & 63, wave = t >> 6;
  __shared__ float rmax[4], rsum[4];
  float v[8];
  float m = -1e30f;
#pragma unroll
  for (int i = 0; i < 8; ++i) {
    v[i] = logits[(size_t)b * M_DIM + i * 256 + t] + bias[i * 256 + t];
    m = fmaxf(m, v[i]);
  }
#pragma unroll
  for (int off = 32; off >= 1; off >>= 1) m = fmaxf(m, __shfl_xor(m, off));
  if (lane == 0) rmax[wave] = m;
  __syncthreads();
  m = fmaxf(fmaxf(rmax[0], rmax[1]), fmaxf(rmax[2], rmax[3]));
  float s = 0.f;
#pragma unroll
  for (int i = 0; i < 8; ++i) {
    v[i] = __expf(v[i] - m);
    s += v[i];
  }
#pragma unroll
  for (int off = 32; off >= 1; off >>= 1) s += __shfl_xor(s, off);
  if (lane == 0) rsum[wave] = s;
  __syncthreads();
  s = rsum[0] + rsum[1] + rsum[2] + rsum[3];
  float inv = 1.f / s;
#pragma unroll
  for (int i = 0; i < 8; ++i) attn[(size_t)b * M_DIM + i * 256 + t] = (bf16_t)(v[i] * inv);
}

// ---------------- final blended activation ----------------
__global__ __launch_bounds__(256) void act_kernel(
    const float* __restrict__ moe, const float* __restrict__ rdv,
    const float* __restrict__ aw, float* __restrict__ out) {
  int i = blockIdx.x * 256 + threadIdx.x;
  float w[9], m = -1e30f;
#pragma unroll
  for (int j = 0; j < 9; ++j) { w[j] = aw[j]; m = fmaxf(m, w[j]); }
  float p[9], s = 0.f;
#pragma unroll
  for (int j = 0; j < 9; ++j) { p[j] = expf(w[j] - m); s += p[j]; }
  float inv = 1.f / s;
#pragma unroll
  for (int j = 0; j < 9; ++j) p[j] *= inv;
  float4 mv = ((const float4*)moe)[i];
  float4 rv = ((const float4*)rdv)[i];
  float xs[4] = {mv.x + rv.x, mv.y + rv.y, mv.z + rv.z, mv.w + rv.w};
  float os[4];
#pragma unroll
  for (int q = 0; q < 4; ++q) {
    float xv = xs[q];
    float enx = expf(-xv);
    float ex = expf(xv);
    float sig = 1.f / (1.f + enx);
    float em1 = expm1f(xv);
    float th = tanhf(xv);
    float rl = fmaxf(xv, 0.f);
    float si = xv * sig;
    float ge = 0.5f * xv * (1.f + erff(xv * 0.70710678118654752f));
    float se = 1.0507009873554805f * (xv > 0.f ? xv : 1.6732632423543772f * em1);
    float el = xv > 0.f ? xv : em1;
    float sp = log1pf(ex);
    float mi = xv * tanhf(sp);
    os[q] = p[0] * sig + p[1] * el + p[2] * th + p[3] * rl + p[4] * si + p[5] * ge + p[6] * se + p[7] * mi;
  }
  ((float4*)out)[i] = make_float4(os[0], os[1], os[2], os[3]);
}

extern "C" void kernel_launch(void* const* d_in, const int* in_sizes, int n_in,
                              void* d_out, int out_size, void* d_ws, size_t ws_size,
                              hipStream_t stream) {
  const float* x        = (const float*)d_in[0];
  const float* gate_w   = (const float*)d_in[1];
  const float* expert_w = (const float*)d_in[2];
  const float* expert_b = (const float*)d_in[3];
  const float* conn_w1  = (const float*)d_in[4];
  const float* conn_b1  = (const float*)d_in[5];
  const float* conn_w2  = (const float*)d_in[6];
  const float* conn_b2  = (const float*)d_in[7];
  const float* navg     = (const float*)d_in[8];
  const float* nmask    = (const float*)d_in[9];
  const float* mem_rw   = (const float*)d_in[10];
  const float* mem_rb   = (const float*)d_in[11];
  const float* memory   = (const float*)d_in[12];
  const float* act_w    = (const float*)d_in[13];
  float* out = (float*)d_out;

  char* ws = (char*)d_ws;
  // persistent-within-call buffers
  bf16_t* wbT  = (bf16_t*)(ws + 0);                    // 8*2048*1024*2 = 33554432
  bf16_t* mrT  = (bf16_t*)(ws + 33554432);             // 2048*2048*2  = 8388608
  bf16_t* memT = (bf16_t*)(ws + 41943040);             // 8388608
  float*  gateb = (float*)(ws + 50331648);             // 32768
  float*  connb = (float*)(ws + 50364416);             // 65536
  float*  moe   = (float*)(ws + 50429952);             // 8388608   (total 58818560)
  // aliased onto wbT region (dead after expert GEMM)
  float*  logits = (float*)(ws + 0);                   // 8388608
  bf16_t* attn   = (bf16_t*)(ws + 8388608);            // 4194304
  float*  readv  = (float*)(ws + 12582912);            // 8388608 (ends 20971520 < 33554432)

  // 1. transposed bf16 weights
  transpose_cvt_kernel<<<dim3(32, 16, 8), 256, 0, stream>>>(expert_w, wbT, D_DIM, H_DIM);
  transpose_cvt_kernel<<<dim3(32, 32, 1), 256, 0, stream>>>(mem_rw, mrT, H_DIM, M_DIM);
  transpose_cvt_kernel<<<dim3(32, 32, 1), 256, 0, stream>>>(memory, memT, M_DIM, H_DIM);
  // 2. gate + conn
  gate_kernel<<<dim3(B_DIM), 256, 0, stream>>>(x, gate_w, gateb);
  conn_kernel<<<dim3(E_DIM), 256, 0, stream>>>(navg, conn_w1, conn_b1, conn_w2, conn_b2, nmask, connb);
  // 3. expert GEMM with fused epilogue, atomic combine into moe
  hipMemsetAsync(moe, 0, (size_t)B_DIM * H_DIM * 4, stream);
  gemm_kernel<1, 0><<<dim3(16, 16, 8), 256, 0, stream>>>(
      x, wbT, moe, D_DIM, D_DIM, H_DIM, (size_t)H_DIM * D_DIM, gateb, connb, expert_b);
  // 4. memory attention
  gemm_kernel<1, 1><<<dim3(16, 16, 1), 256, 0, stream>>>(
      moe, mrT, logits, H_DIM, H_DIM, M_DIM, 0, nullptr, nullptr, nullptr);
  softmax_kernel<<<dim3(B_DIM), 256, 0, stream>>>(logits, mem_rb, attn);
  gemm_kernel<0, 1><<<dim3(16, 16, 1), 256, 0, stream>>>(
      attn, memT, readv, M_DIM, M_DIM, H_DIM, 0, nullptr, nullptr, nullptr);
  // 5. blended activation
  act_kernel<<<dim3((B_DIM * H_DIM) / (256 * 4)), 256, 0, stream>>>(moe, readv, act_w, out);
}

// Round 2
// 258.555 us; speedup vs baseline: 1.3378x; 1.3378x over previous
//
#include <hip/hip_runtime.h>
#include <hip/hip_bf16.h>
#include <math.h>

typedef __bf16 bf16_t;
typedef __bf16 bf16x8 __attribute__((ext_vector_type(8)));
typedef __bf16 bf16x4 __attribute__((ext_vector_type(4)));
typedef float f32x4 __attribute__((ext_vector_type(4)));

#define B_DIM 1024
#define D_DIM 1024
#define H_DIM 2048
#define E_DIM 8
#define M_DIM 2048

typedef const __attribute__((address_space(1))) unsigned int as1_uint;
typedef __attribute__((address_space(3))) unsigned int as3_uint;

__device__ __forceinline__ void gl_lds16(const void* g, void* l) {
  __builtin_amdgcn_global_load_lds((as1_uint*)g, (as3_uint*)l, 16, 0, 0);
}

// ---------------- f32 -> bf16 convert (vectorized, 8 elems/thread) ----------------
__global__ __launch_bounds__(256) void cvt_kernel(const float* __restrict__ in,
                                                  bf16_t* __restrict__ out) {
  size_t i = ((size_t)blockIdx.x * 256 + threadIdx.x) * 8;
  float4 a = *(const float4*)&in[i];
  float4 b = *(const float4*)&in[i + 4];
  bf16x8 o;
  o[0] = (bf16_t)a.x; o[1] = (bf16_t)a.y; o[2] = (bf16_t)a.z; o[3] = (bf16_t)a.w;
  o[4] = (bf16_t)b.x; o[5] = (bf16_t)b.y; o[6] = (bf16_t)b.z; o[7] = (bf16_t)b.w;
  *(bf16x8*)&out[i] = o;
}

// ---------------- transpose + f32->bf16 convert: in [R][C] f32 -> out [C][R] bf16 ----------------
__global__ __launch_bounds__(256) void transpose_cvt_kernel(
    const float* __restrict__ in, bf16_t* __restrict__ out, int R, int C) {
  __shared__ float tile[64][65];
  const size_t matsz = (size_t)R * C;
  const float* inp = in + matsz * blockIdx.z;
  bf16_t* outp = out + matsz * blockIdx.z;
  int c0 = blockIdx.x * 64, r0 = blockIdx.y * 64;
  int tx = threadIdx.x & 63, ty = threadIdx.x >> 6;
#pragma unroll
  for (int i = 0; i < 16; ++i) {
    int r = ty + i * 4;
    tile[r][tx] = inp[(size_t)(r0 + r) * C + c0 + tx];
  }
  __syncthreads();
#pragma unroll
  for (int i = 0; i < 16; ++i) {
    int c = ty + i * 4;
    outp[(size_t)(c0 + c) * R + r0 + tx] = (bf16_t)tile[tx][c];
  }
}

// ---------------- gate: softmax(x @ gate_w) -> gate [B][E] f32 ----------------
__global__ __launch_bounds__(256) void gate_kernel(
    const float* __restrict__ x, const float* __restrict__ gw, float* __restrict__ gate) {
  __shared__ float red[256][8];
  int b = blockIdx.x, t = threadIdx.x;
  float acc[8] = {0.f, 0.f, 0.f, 0.f, 0.f, 0.f, 0.f, 0.f};
  for (int d = t; d < D_DIM; d += 256) {
    float xv = x[(size_t)b * D_DIM + d];
#pragma unroll
    for (int e = 0; e < 8; ++e) acc[e] += xv * gw[d * 8 + e];
  }
#pragma unroll
  for (int e = 0; e < 8; ++e) red[t][e] = acc[e];
  __syncthreads();
  for (int s = 128; s > 0; s >>= 1) {
    if (t < s) {
#pragma unroll
      for (int e = 0; e < 8; ++e) red[t][e] += red[t + s][e];
    }
    __syncthreads();
  }
  if (t == 0) {
    float m = red[0][0];
#pragma unroll
    for (int e = 1; e < 8; ++e) m = fmaxf(m, red[0][e]);
    float p[8], sum = 0.f;
#pragma unroll
    for (int e = 0; e < 8; ++e) { p[e] = expf(red[0][e] - m); sum += p[e]; }
    float inv = 1.f / sum;
#pragma unroll
    for (int e = 0; e < 8; ++e) gate[b * 8 + e] = p[e] * inv;
  }
}

// ---------------- conn gate per expert ----------------
__global__ __launch_bounds__(256) void conn_kernel(
    const float* __restrict__ avg, const float* __restrict__ w1, const float* __restrict__ b1,
    const float* __restrict__ w2, const float* __restrict__ b2, const float* __restrict__ mask,
    float* __restrict__ conn) {
  __shared__ float red[256 * 32];
  __shared__ float h1[32];
  int e = blockIdx.x, t = threadIdx.x;
  float acc[32];
#pragma unroll
  for (int k = 0; k < 32; ++k) acc[k] = 0.f;
  for (int h = t; h < H_DIM; h += 256) {
    float av = avg[e * H_DIM + h];
    const float* w1p = &w1[((size_t)e * H_DIM + h) * 32];
#pragma unroll
    for (int k = 0; k < 32; ++k) acc[k] += av * w1p[k];
  }
#pragma unroll
  for (int k = 0; k < 32; ++k) red[t * 32 + k] = acc[k];
  __syncthreads();
  for (int s = 128; s > 0; s >>= 1) {
    if (t < s) {
#pragma unroll
      for (int k = 0; k < 32; ++k) red[t * 32 + k] += red[(t + s) * 32 + k];
    }
    __syncthreads();
  }
  if (t < 32) h1[t] = fmaxf(red[t] + b1[e * 32 + t], 0.f);
  __syncthreads();
  for (int h = t; h < H_DIM; h += 256) {
    float s = b2[e * H_DIM + h];
#pragma unroll
    for (int k = 0; k < 32; ++k) s += h1[k] * w2[((size_t)e * 32 + k) * H_DIM + h];
    conn[e * H_DIM + h] = (1.f / (1.f + expf(-s))) * mask[e * H_DIM + h];
  }
}

// ---------------- m97-structure GEMM: 128x128 tile, BK=64, global_load_lds staging ----------------
// A [1024][lda] bf16 k-major, Bt [Ncols][ldb] bf16 k-major. 16 K-steps of 64 starting at kbase.
// EPI 0: expert epilogue (bias/conn/relu/gate + atomicAdd into moe), ez = expert.
// EPI 1: split-K atomicAdd store, ez = k-half index (kbase = ez*1024).
template <int EPI>
__global__ __launch_bounds__(256, 2) void gemm128(
    const bf16_t* __restrict__ A, const bf16_t* __restrict__ Bt, float* __restrict__ C,
    int lda, int ldb, int ldc, size_t strideB,
    const float* __restrict__ gate, const float* __restrict__ conn,
    const float* __restrict__ ebias) {
  __shared__ bf16_t As[128 * 64];
  __shared__ bf16_t Bs[128 * 64];

  // bijective XCD swizzle: nwg divisible by 8; each XCD gets a contiguous work chunk
  const int nwg = gridDim.x;
  const int cpx = nwg >> 3;
  const int wid = (blockIdx.x & 7) * cpx + (blockIdx.x >> 3);
  const int ez = wid >> 7;           // expert (EPI0) or k-half (EPI1)
  const int rem = wid & 127;
  const int b0 = (rem & 7) * 128;    // m fastest: same-(n,ez) m-blocks contiguous -> same XCD
  const int n0 = (rem >> 3) * 128;
  const int kbase = (EPI == 0) ? 0 : ez * 1024;
  const bf16_t* Bp = Bt + ((EPI == 0) ? strideB * (size_t)ez : 0);

  const int t = threadIdx.x;
  const int lane = t & 63, wave = t >> 6;
  const int wm = wave >> 1, wn = wave & 1;
  const int lr = lane & 15, lk = (lane >> 4) * 8;
  const int srow = (lane >> 3);          // staging row within 8-row wave chunk
  const int scol = (lane & 7) * 8;       // staging col (elems)

  const f32x4 zv = {0.f, 0.f, 0.f, 0.f};
  f32x4 acc[4][4];
#pragma unroll
  for (int mf = 0; mf < 4; ++mf)
#pragma unroll
    for (int nf = 0; nf < 4; ++nf) acc[mf][nf] = zv;

  for (int kt = 0; kt < 16; ++kt) {
    const int k0 = kbase + (kt << 6);
    const bf16_t* Ag = A + (size_t)b0 * lda + k0;
    const bf16_t* Bg = Bp + (size_t)n0 * ldb + k0;
#pragma unroll
    for (int i = 0; i < 4; ++i) {
      int rbase = i * 32 + wave * 8;
      gl_lds16(Ag + (size_t)(rbase + srow) * lda + scol, &As[rbase * 64]);
      gl_lds16(Bg + (size_t)(rbase + srow) * ldb + scol, &Bs[rbase * 64]);
    }
    __syncthreads();
#pragma unroll
    for (int kk = 0; kk < 2; ++kk) {
      bf16x8 af[4], bfr[4];
#pragma unroll
      for (int mf = 0; mf < 4; ++mf)
        af[mf] = *(const bf16x8*)&As[(wm * 64 + mf * 16 + lr) * 64 + kk * 32 + lk];
#pragma unroll
      for (int nf = 0; nf < 4; ++nf)
        bfr[nf] = *(const bf16x8*)&Bs[(wn * 64 + nf * 16 + lr) * 64 + kk * 32 + lk];
#pragma unroll
      for (int mf = 0; mf < 4; ++mf)
#pragma unroll
        for (int nf = 0; nf < 4; ++nf)
          acc[mf][nf] = __builtin_amdgcn_mfma_f32_16x16x32_bf16(af[mf], bfr[nf], acc[mf][nf], 0, 0, 0);
    }
    __syncthreads();
  }

  const int r4 = (lane >> 4) * 4;
#pragma unroll
  for (int mf = 0; mf < 4; ++mf) {
#pragma unroll
    for (int nf = 0; nf < 4; ++nf) {
      int gcol = n0 + wn * 64 + nf * 16 + lr;
      float cm = 0.f, bb = 0.f;
      if (EPI == 0) {
        cm = conn[ez * H_DIM + gcol];
        bb = ebias[ez * H_DIM + gcol];
      }
#pragma unroll
      for (int j = 0; j < 4; ++j) {
        int grow = b0 + wm * 64 + mf * 16 + r4 + j;
        float v = acc[mf][nf][j];
        if (EPI == 0) {
          float g = gate[grow * E_DIM + ez];
          v = fmaxf((v + bb) * cm, 0.f) * g;
        }
        atomicAdd(&C[(size_t)grow * ldc + gcol], v);
      }
    }
  }
}

// ---------------- softmax over M with bias -> bf16 attn ----------------
__global__ __launch_bounds__(256) void softmax_kernel(
    const float* __restrict__ logits, const float* __restrict__ bias, bf16_t* __restrict__ attn) {
  int b = blockIdx.x, t = threadIdx.x;
  int lane = t & 63, wave = t >> 6;
  __shared__ float rmax[4], rsum[4];
  float v[8];
  float m = -1e30f;
#pragma unroll
  for (int i = 0; i < 8; ++i) {
    v[i] = logits[(size_t)b * M_DIM + i * 256 + t] + bias[i * 256 + t];
    m = fmaxf(m, v[i]);
  }
#pragma unroll
  for (int off = 32; off >= 1; off >>= 1) m = fmaxf(m, __shfl_xor(m, off));
  if (lane == 0) rmax[wave] = m;
  __syncthreads();
  m = fmaxf(fmaxf(rmax[0], rmax[1]), fmaxf(rmax[2], rmax[3]));
  float s = 0.f;
#pragma unroll
  for (int i = 0; i < 8; ++i) {
    v[i] = __expf(v[i] - m);
    s += v[i];
  }
#pragma unroll
  for (int off = 32; off >= 1; off >>= 1) s += __shfl_xor(s, off);
  if (lane == 0) rsum[wave] = s;
  __syncthreads();
  s = rsum[0] + rsum[1] + rsum[2] + rsum[3];
  float inv = 1.f / s;
#pragma unroll
  for (int i = 0; i < 8; ++i) attn[(size_t)b * M_DIM + i * 256 + t] = (bf16_t)(v[i] * inv);
}

// ---------------- final blended activation (in-place: out = act(out + rdv)) ----------------
__global__ __launch_bounds__(256) void act_kernel(
    const float* __restrict__ rdv, const float* __restrict__ aw, float* __restrict__ out) {
  int i = blockIdx.x * 256 + threadIdx.x;
  float w[9], m = -1e30f;
#pragma unroll
  for (int j = 0; j < 9; ++j) { w[j] = aw[j]; m = fmaxf(m, w[j]); }
  float p[9], s = 0.f;
#pragma unroll
  for (int j = 0; j < 9; ++j) { p[j] = expf(w[j] - m); s += p[j]; }
  float inv = 1.f / s;
#pragma unroll
  for (int j = 0; j < 9; ++j) p[j] *= inv;
  float4 mv = ((const float4*)out)[i];
  float4 rv = ((const float4*)rdv)[i];
  float xs[4] = {mv.x + rv.x, mv.y + rv.y, mv.z + rv.z, mv.w + rv.w};
  float os[4];
#pragma unroll
  for (int q = 0; q < 4; ++q) {
    float xv = xs[q];
    float enx = expf(-xv);
    float ex = expf(xv);
    float sig = 1.f / (1.f + enx);
    float em1 = expm1f(xv);
    float th = tanhf(xv);
    float rl = fmaxf(xv, 0.f);
    float si = xv * sig;
    float ge = 0.5f * xv * (1.f + erff(xv * 0.70710678118654752f));
    float se = 1.0507009873554805f * (xv > 0.f ? xv : 1.6732632423543772f * em1);
    float el = xv > 0.f ? xv : em1;
    float sp = log1pf(ex);
    float mi = xv * tanhf(sp);
    os[q] = p[0] * sig + p[1] * el + p[2] * th + p[3] * rl + p[4] * si + p[5] * ge + p[6] * se + p[7] * mi;
  }
  ((float4*)out)[i] = make_float4(os[0], os[1], os[2], os[3]);
}

extern "C" void kernel_launch(void* const* d_in, const int* in_sizes, int n_in,
                              void* d_out, int out_size, void* d_ws, size_t ws_size,
                              hipStream_t stream) {
  const float* x        = (const float*)d_in[0];
  const float* gate_w   = (const float*)d_in[1];
  const float* expert_w = (const float*)d_in[2];
  const float* expert_b = (const float*)d_in[3];
  const float* conn_w1  = (const float*)d_in[4];
  const float* conn_b1  = (const float*)d_in[5];
  const float* conn_w2  = (const float*)d_in[6];
  const float* conn_b2  = (const float*)d_in[7];
  const float* navg     = (const float*)d_in[8];
  const float* nmask    = (const float*)d_in[9];
  const float* mem_rw   = (const float*)d_in[10];
  const float* mem_rb   = (const float*)d_in[11];
  const float* memory   = (const float*)d_in[12];
  const float* act_w    = (const float*)d_in[13];
  float* out = (float*)d_out;

  char* ws = (char*)d_ws;
  // persistent-within-call buffers
  bf16_t* wbT   = (bf16_t*)(ws + 0);            // 8*2048*1024*2 = 33554432
  bf16_t* mrT   = (bf16_t*)(ws + 33554432);     // [M][H] 2048*2048*2 = 8388608
  bf16_t* memT  = (bf16_t*)(ws + 41943040);     // [H][M] 8388608
  float*  gateb = (float*)(ws + 50331648);      // 32768
  float*  connb = (float*)(ws + 50364416);      // 65536
  bf16_t* x_bf  = (bf16_t*)(ws + 50429952);     // 2097152   (ends 52527104)
  // aliased onto wbT region (dead after expert GEMM)
  float*  logits = (float*)(ws + 0);            // 8388608
  bf16_t* attn   = (bf16_t*)(ws + 8388608);     // 4194304
  float*  readv  = (float*)(ws + 12582912);     // 8388608
  bf16_t* moe_bf = (bf16_t*)(ws + 20971520);    // 4194304  (ends 25165824 < 33554432)
  float*  moe    = out;                          // [B][H] f32 lives in d_out

  // 1. one-time conversions / transposes
  cvt_kernel<<<dim3(512), 256, 0, stream>>>(x, x_bf);
  transpose_cvt_kernel<<<dim3(32, 16, 8), 256, 0, stream>>>(expert_w, wbT, D_DIM, H_DIM);
  transpose_cvt_kernel<<<dim3(32, 32, 1), 256, 0, stream>>>(mem_rw, mrT, H_DIM, M_DIM);
  transpose_cvt_kernel<<<dim3(32, 32, 1), 256, 0, stream>>>(memory, memT, M_DIM, H_DIM);
  // 2. gate + conn
  gate_kernel<<<dim3(B_DIM), 256, 0, stream>>>(x, gate_w, gateb);
  conn_kernel<<<dim3(E_DIM), 256, 0, stream>>>(navg, conn_w1, conn_b1, conn_w2, conn_b2, nmask, connb);
  // 3. expert GEMM with fused epilogue, atomic combine into moe (=d_out)
  hipMemsetAsync(moe, 0, (size_t)B_DIM * H_DIM * 4, stream);
  gemm128<0><<<dim3(1024), 256, 0, stream>>>(
      x_bf, wbT, moe, D_DIM, D_DIM, H_DIM, (size_t)H_DIM * D_DIM, gateb, connb, expert_b);
  // 4. memory attention (split-K x2 per GEMM)
  cvt_kernel<<<dim3(1024), 256, 0, stream>>>(moe, moe_bf);
  hipMemsetAsync(logits, 0, (size_t)B_DIM * M_DIM * 4, stream);
  gemm128<1><<<dim3(256), 256, 0, stream>>>(
      moe_bf, mrT, logits, H_DIM, H_DIM, M_DIM, 0, nullptr, nullptr, nullptr);
  softmax_kernel<<<dim3(B_DIM), 256, 0, stream>>>(logits, mem_rb, attn);
  hipMemsetAsync(readv, 0, (size_t)B_DIM * H_DIM * 4, stream);
  gemm128<1><<<dim3(256), 256, 0, stream>>>(
      attn, memT, readv, M_DIM, M_DIM, H_DIM, 0, nullptr, nullptr, nullptr);
  // 5. blended activation (in-place on d_out)
  act_kernel<<<dim3((B_DIM * H_DIM) / (256 * 4)), 256, 0, stream>>>(readv, act_w, out);
}

// Round 3
// 249.457 us; speedup vs baseline: 1.3865x; 1.0365x over previous
//
#include <hip/hip_runtime.h>
#include <hip/hip_bf16.h>
#include <math.h>

typedef __bf16 bf16_t;
typedef __bf16 bf16x8 __attribute__((ext_vector_type(8)));
typedef float f32x4 __attribute__((ext_vector_type(4)));

#define B_DIM 1024
#define D_DIM 1024
#define H_DIM 2048
#define E_DIM 8
#define M_DIM 2048

typedef const __attribute__((address_space(1))) unsigned int as1_uint;
typedef __attribute__((address_space(3))) unsigned int as3_uint;

__device__ __forceinline__ void gl_lds16(const void* g, void* l) {
  __builtin_amdgcn_global_load_lds((as1_uint*)g, (as3_uint*)l, 16, 0, 0);
}

// ---------------- f32 -> bf16 convert (8 elems/thread) ----------------
__global__ __launch_bounds__(256) void cvt_kernel(const float* __restrict__ in,
                                                  bf16_t* __restrict__ out) {
  size_t i = ((size_t)blockIdx.x * 256 + threadIdx.x) * 8;
  float4 a = *(const float4*)&in[i];
  float4 b = *(const float4*)&in[i + 4];
  bf16x8 o;
  o[0] = (bf16_t)a.x; o[1] = (bf16_t)a.y; o[2] = (bf16_t)a.z; o[3] = (bf16_t)a.w;
  o[4] = (bf16_t)b.x; o[5] = (bf16_t)b.y; o[6] = (bf16_t)b.z; o[7] = (bf16_t)b.w;
  *(bf16x8*)&out[i] = o;
}

// ---------------- transpose + cvt: in [R][C] f32 -> out [C][R] bf16 (64x64 tiles) ----------------
__global__ __launch_bounds__(256) void transpose_cvt_kernel(
    const float* __restrict__ in, bf16_t* __restrict__ out, int R, int C) {
  __shared__ float tile[64][65];
  const size_t matsz = (size_t)R * C;
  const float* inp = in + matsz * blockIdx.z;
  bf16_t* outp = out + matsz * blockIdx.z;
  int c0 = blockIdx.x * 64, r0 = blockIdx.y * 64;
  int t = threadIdx.x;
  int cq = (t & 15) * 4, rr = t >> 4;
#pragma unroll
  for (int i = 0; i < 4; ++i) {
    int r = rr + 16 * i;
    float4 v = *(const float4*)&inp[(size_t)(r0 + r) * C + c0 + cq];
    tile[r][cq] = v.x; tile[r][cq + 1] = v.y; tile[r][cq + 2] = v.z; tile[r][cq + 3] = v.w;
  }
  __syncthreads();
  int r8 = (t & 7) * 8, cc = t >> 3;
#pragma unroll
  for (int i = 0; i < 2; ++i) {
    int c = cc + 32 * i;
    bf16x8 o;
#pragma unroll
    for (int j = 0; j < 8; ++j) o[j] = (bf16_t)tile[r8 + j][c];
    *(bf16x8*)&outp[(size_t)(c0 + c) * R + r0 + r8] = o;
  }
}

// ---------------- gate: softmax(x @ gate_w) -> gate [B][E] f32 ----------------
__global__ __launch_bounds__(256) void gate_kernel(
    const float* __restrict__ x, const float* __restrict__ gw, float* __restrict__ gate) {
  __shared__ float red[256][8];
  int b = blockIdx.x, t = threadIdx.x;
  float acc[8] = {0.f, 0.f, 0.f, 0.f, 0.f, 0.f, 0.f, 0.f};
  for (int d = t; d < D_DIM; d += 256) {
    float xv = x[(size_t)b * D_DIM + d];
#pragma unroll
    for (int e = 0; e < 8; ++e) acc[e] += xv * gw[d * 8 + e];
  }
#pragma unroll
  for (int e = 0; e < 8; ++e) red[t][e] = acc[e];
  __syncthreads();
  for (int s = 128; s > 0; s >>= 1) {
    if (t < s) {
#pragma unroll
      for (int e = 0; e < 8; ++e) red[t][e] += red[t + s][e];
    }
    __syncthreads();
  }
  if (t == 0) {
    float m = red[0][0];
#pragma unroll
    for (int e = 1; e < 8; ++e) m = fmaxf(m, red[0][e]);
    float p[8], sum = 0.f;
#pragma unroll
    for (int e = 0; e < 8; ++e) { p[e] = expf(red[0][e] - m); sum += p[e]; }
    float inv = 1.f / sum;
#pragma unroll
    for (int e = 0; e < 8; ++e) gate[b * 8 + e] = p[e] * inv;
  }
}

// ---------------- conn gate per expert ----------------
__global__ __launch_bounds__(256) void conn_kernel(
    const float* __restrict__ avg, const float* __restrict__ w1, const float* __restrict__ b1,
    const float* __restrict__ w2, const float* __restrict__ b2, const float* __restrict__ mask,
    float* __restrict__ conn) {
  __shared__ float red[256 * 32];
  __shared__ float h1[32];
  int e = blockIdx.x, t = threadIdx.x;
  float acc[32];
#pragma unroll
  for (int k = 0; k < 32; ++k) acc[k] = 0.f;
  for (int h = t; h < H_DIM; h += 256) {
    float av = avg[e * H_DIM + h];
    const float* w1p = &w1[((size_t)e * H_DIM + h) * 32];
#pragma unroll
    for (int k = 0; k < 32; ++k) acc[k] += av * w1p[k];
  }
#pragma unroll
  for (int k = 0; k < 32; ++k) red[t * 32 + k] = acc[k];
  __syncthreads();
  for (int s = 128; s > 0; s >>= 1) {
    if (t < s) {
#pragma unroll
      for (int k = 0; k < 32; ++k) red[t * 32 + k] += red[(t + s) * 32 + k];
    }
    __syncthreads();
  }
  if (t < 32) h1[t] = fmaxf(red[t] + b1[e * 32 + t], 0.f);
  __syncthreads();
  for (int h = t; h < H_DIM; h += 256) {
    float s = b2[e * H_DIM + h];
#pragma unroll
    for (int k = 0; k < 32; ++k) s += h1[k] * w2[((size_t)e * 32 + k) * H_DIM + h];
    conn[e * H_DIM + h] = (1.f / (1.f + expf(-s))) * mask[e * H_DIM + h];
  }
}

// ---------------- 2-phase dbuf GEMM: 128x128 tile, BK=64, swizzled LDS, 16 K-tiles ----------------
// EPI 0: expert epilogue, ez = expert, kbase = 0.  EPI 1: split-K, ez = k-half, kbase = ez*1024.
template <int EPI>
__global__ __launch_bounds__(256, 2) void gemm128(
    const bf16_t* __restrict__ A, const bf16_t* __restrict__ Bt, float* __restrict__ C,
    int lda, int ldb, int ldc, size_t strideB,
    const float* __restrict__ gate, const float* __restrict__ conn,
    const float* __restrict__ ebias) {
  __shared__ bf16_t As[2][128 * 64];
  __shared__ bf16_t Bs[2][128 * 64];

  const int nwg = gridDim.x;
  const int cpx = nwg >> 3;
  const int wid = (blockIdx.x & 7) * cpx + (blockIdx.x >> 3);
  const int ez = wid >> 7;
  const int rem = wid & 127;
  const int b0 = (rem & 7) * 128;
  const int n0 = (rem >> 3) * 128;
  const int kbase = (EPI == 0) ? 0 : (ez << 10);

  const int t = threadIdx.x;
  const int lane = t & 63, wave = t >> 6;
  const int wm = wave >> 1, wn = wave & 1;
  const int lr = lane & 15, lk = (lane >> 4) * 8;
  const int csw = (lr & 7) << 3;                       // read-side XOR (elem units)
  const int srow = lane >> 3;
  const int scol = ((lane & 7) ^ (lane >> 3)) << 3;    // pre-swizzled source col (elems)

  const bf16_t* Arow = A + (size_t)(b0 + srow) * lda + kbase + scol;
  const bf16_t* Brow = Bt + ((EPI == 0) ? strideB * (size_t)ez : 0) +
                       (size_t)(n0 + srow) * ldb + kbase + scol;

  const f32x4 zv = {0.f, 0.f, 0.f, 0.f};
  f32x4 acc[4][4];
#pragma unroll
  for (int mf = 0; mf < 4; ++mf)
#pragma unroll
    for (int nf = 0; nf < 4; ++nf) acc[mf][nf] = zv;

  auto STAGE = [&](int bsel, int kt) {
    const int ko = kt << 6;
#pragma unroll
    for (int i = 0; i < 4; ++i) {
      int rb = i * 32 + wave * 8;
      gl_lds16(Arow + (size_t)rb * lda + ko, &As[bsel][rb * 64]);
      gl_lds16(Brow + (size_t)rb * ldb + ko, &Bs[bsel][rb * 64]);
    }
  };

  auto COMPUTE = [&](int bsel) {
    bf16x8 bfr[2][4];
#pragma unroll
    for (int kk = 0; kk < 2; ++kk)
#pragma unroll
      for (int nf = 0; nf < 4; ++nf)
        bfr[kk][nf] = *(const bf16x8*)&Bs[bsel][(wn * 64 + nf * 16 + lr) * 64 + ((kk * 32 + lk) ^ csw)];
    __builtin_amdgcn_s_setprio(1);
#pragma unroll
    for (int mf = 0; mf < 4; ++mf) {
      bf16x8 a0 = *(const bf16x8*)&As[bsel][(wm * 64 + mf * 16 + lr) * 64 + (lk ^ csw)];
      bf16x8 a1 = *(const bf16x8*)&As[bsel][(wm * 64 + mf * 16 + lr) * 64 + ((32 + lk) ^ csw)];
#pragma unroll
      for (int nf = 0; nf < 4; ++nf)
        acc[mf][nf] = __builtin_amdgcn_mfma_f32_16x16x32_bf16(a0, bfr[0][nf], acc[mf][nf], 0, 0, 0);
#pragma unroll
      for (int nf = 0; nf < 4; ++nf)
        acc[mf][nf] = __builtin_amdgcn_mfma_f32_16x16x32_bf16(a1, bfr[1][nf], acc[mf][nf], 0, 0, 0);
    }
    __builtin_amdgcn_s_setprio(0);
  };

  STAGE(0, 0);
  __syncthreads();
  for (int kt = 0; kt < 15; ++kt) {
    STAGE((kt + 1) & 1, kt + 1);
    COMPUTE(kt & 1);
    __syncthreads();
  }
  COMPUTE(1);

  const int r4 = (lane >> 4) * 4;
#pragma unroll
  for (int mf = 0; mf < 4; ++mf) {
#pragma unroll
    for (int nf = 0; nf < 4; ++nf) {
      int gcol = n0 + wn * 64 + nf * 16 + lr;
      float cm = 0.f, bb = 0.f;
      if (EPI == 0) {
        cm = conn[ez * H_DIM + gcol];
        bb = ebias[ez * H_DIM + gcol];
      }
#pragma unroll
      for (int j = 0; j < 4; ++j) {
        int grow = b0 + wm * 64 + mf * 16 + r4 + j;
        float v = acc[mf][nf][j];
        if (EPI == 0) {
          float g = gate[grow * E_DIM + ez];
          v = fmaxf((v + bb) * cm, 0.f) * g;
        }
        unsafeAtomicAdd(&C[(size_t)grow * ldc + gcol], v);
      }
    }
  }
}

// ---------------- softmax over M with bias -> bf16 attn ----------------
__global__ __launch_bounds__(256) void softmax_kernel(
    const float* __restrict__ logits, const float* __restrict__ bias, bf16_t* __restrict__ attn) {
  int b = blockIdx.x, t = threadIdx.x;
  int lane = t & 63, wave = t >> 6;
  __shared__ float rmax[4], rsum[4];
  float v[8];
  float m = -1e30f;
#pragma unroll
  for (int i = 0; i < 8; ++i) {
    v[i] = logits[(size_t)b * M_DIM + i * 256 + t] + bias[i * 256 + t];
    m = fmaxf(m, v[i]);
  }
#pragma unroll
  for (int off = 32; off >= 1; off >>= 1) m = fmaxf(m, __shfl_xor(m, off));
  if (lane == 0) rmax[wave] = m;
  __syncthreads();
  m = fmaxf(fmaxf(rmax[0], rmax[1]), fmaxf(rmax[2], rmax[3]));
  float s = 0.f;
#pragma unroll
  for (int i = 0; i < 8; ++i) {
    v[i] = __expf(v[i] - m);
    s += v[i];
  }
#pragma unroll
  for (int off = 32; off >= 1; off >>= 1) s += __shfl_xor(s, off);
  if (lane == 0) rsum[wave] = s;
  __syncthreads();
  s = rsum[0] + rsum[1] + rsum[2] + rsum[3];
  float inv = 1.f / s;
#pragma unroll
  for (int i = 0; i < 8; ++i) attn[(size_t)b * M_DIM + i * 256 + t] = (bf16_t)(v[i] * inv);
}

// ---------------- final blended activation (in-place: out = act(out + rdv)) ----------------
__global__ __launch_bounds__(256) void act_kernel(
    const float* __restrict__ rdv, const float* __restrict__ aw, float* __restrict__ out) {
  int i = blockIdx.x * 256 + threadIdx.x;
  float w[9], m = -1e30f;
#pragma unroll
  for (int j = 0; j < 9; ++j) { w[j] = aw[j]; m = fmaxf(m, w[j]); }
  float p[9], s = 0.f;
#pragma unroll
  for (int j = 0; j < 9; ++j) { p[j] = expf(w[j] - m); s += p[j]; }
  float inv = 1.f / s;
#pragma unroll
  for (int j = 0; j < 9; ++j) p[j] *= inv;
  float4 mv = ((const float4*)out)[i];
  float4 rv = ((const float4*)rdv)[i];
  float xs[4] = {mv.x + rv.x, mv.y + rv.y, mv.z + rv.z, mv.w + rv.w};
  float os[4];
#pragma unroll
  for (int q = 0; q < 4; ++q) {
    float xv = xs[q];
    float enx = expf(-xv);
    float ex = expf(xv);
    float sig = 1.f / (1.f + enx);
    float em1 = expm1f(xv);
    float th = tanhf(xv);
    float rl = fmaxf(xv, 0.f);
    float si = xv * sig;
    float ge = 0.5f * xv * (1.f + erff(xv * 0.70710678118654752f));
    float se = 1.0507009873554805f * (xv > 0.f ? xv : 1.6732632423543772f * em1);
    float el = xv > 0.f ? xv : em1;
    float sp = log1pf(ex);
    float mi = xv * tanhf(sp);
    os[q] = p[0] * sig + p[1] * el + p[2] * th + p[3] * rl + p[4] * si + p[5] * ge + p[6] * se + p[7] * mi;
  }
  ((float4*)out)[i] = make_float4(os[0], os[1], os[2], os[3]);
}

extern "C" void kernel_launch(void* const* d_in, const int* in_sizes, int n_in,
                              void* d_out, int out_size, void* d_ws, size_t ws_size,
                              hipStream_t stream) {
  const float* x        = (const float*)d_in[0];
  const float* gate_w   = (const float*)d_in[1];
  const float* expert_w = (const float*)d_in[2];
  const float* expert_b = (const float*)d_in[3];
  const float* conn_w1  = (const float*)d_in[4];
  const float* conn_b1  = (const float*)d_in[5];
  const float* conn_w2  = (const float*)d_in[6];
  const float* conn_b2  = (const float*)d_in[7];
  const float* navg     = (const float*)d_in[8];
  const float* nmask    = (const float*)d_in[9];
  const float* mem_rw   = (const float*)d_in[10];
  const float* mem_rb   = (const float*)d_in[11];
  const float* memory   = (const float*)d_in[12];
  const float* act_w    = (const float*)d_in[13];
  float* out = (float*)d_out;

  char* ws = (char*)d_ws;
  // persistent-within-call buffers
  bf16_t* wbT   = (bf16_t*)(ws + 0);            // 8*2048*1024*2 = 33554432
  bf16_t* mrT   = (bf16_t*)(ws + 33554432);     // [M][H] 8388608
  bf16_t* memT  = (bf16_t*)(ws + 41943040);     // [H][M] 8388608
  float*  gateb = (float*)(ws + 50331648);      // 32768
  float*  connb = (float*)(ws + 50364416);      // 65536
  bf16_t* x_bf  = (bf16_t*)(ws + 50429952);     // 2097152 (ends 52527104)
  // aliased onto wbT region (dead after expert GEMM)
  float*  logits = (float*)(ws + 0);            // 8388608
  bf16_t* attn   = (bf16_t*)(ws + 8388608);     // 4194304
  float*  readv  = (float*)(ws + 12582912);     // 8388608
  bf16_t* moe_bf = (bf16_t*)(ws + 20971520);    // 4194304 (ends 25165824 < 33554432)
  float*  moe    = out;                          // [B][H] f32 lives in d_out

  // 1. one-time conversions / transposes
  cvt_kernel<<<dim3(512), 256, 0, stream>>>(x, x_bf);
  transpose_cvt_kernel<<<dim3(32, 16, 8), 256, 0, stream>>>(expert_w, wbT, D_DIM, H_DIM);
  transpose_cvt_kernel<<<dim3(32, 32, 1), 256, 0, stream>>>(mem_rw, mrT, H_DIM, M_DIM);
  transpose_cvt_kernel<<<dim3(32, 32, 1), 256, 0, stream>>>(memory, memT, M_DIM, H_DIM);
  // 2. gate + conn
  gate_kernel<<<dim3(B_DIM), 256, 0, stream>>>(x, gate_w, gateb);
  conn_kernel<<<dim3(E_DIM), 256, 0, stream>>>(navg, conn_w1, conn_b1, conn_w2, conn_b2, nmask, connb);
  // 3. expert GEMM with fused epilogue, atomic combine into moe (=d_out)
  hipMemsetAsync(moe, 0, (size_t)B_DIM * H_DIM * 4, stream);
  gemm128<0><<<dim3(1024), 256, 0, stream>>>(
      x_bf, wbT, moe, D_DIM, D_DIM, H_DIM, (size_t)H_DIM * D_DIM, gateb, connb, expert_b);
  // 4. memory attention (split-K x2 per GEMM); one merged memset clears logits+attn+readv
  cvt_kernel<<<dim3(1024), 256, 0, stream>>>(moe, moe_bf);
  hipMemsetAsync(ws, 0, 20971520, stream);
  gemm128<1><<<dim3(256), 256, 0, stream>>>(
      moe_bf, mrT, logits, H_DIM, H_DIM, M_DIM, 0, nullptr, nullptr, nullptr);
  softmax_kernel<<<dim3(B_DIM), 256, 0, stream>>>(logits, mem_rb, attn);
  gemm128<1><<<dim3(256), 256, 0, stream>>>(
      attn, memT, readv, M_DIM, M_DIM, H_DIM, 0, nullptr, nullptr, nullptr);
  // 5. blended activation (in-place on d_out)
  act_kernel<<<dim3((B_DIM * H_DIM) / (256 * 4)), 256, 0, stream>>>(readv, act_w, out);
}

// Round 4
// 163.331 us; speedup vs baseline: 2.1177x; 1.5273x over previous
//
#include <hip/hip_runtime.h>
#include <hip/hip_bf16.h>
#include <math.h>

typedef __bf16 bf16_t;
typedef __bf16 bf16x8 __attribute__((ext_vector_type(8)));
typedef float f32x4 __attribute__((ext_vector_type(4)));

#define B_DIM 1024
#define D_DIM 1024
#define H_DIM 2048
#define E_DIM 8
#define M_DIM 2048

typedef const __attribute__((address_space(1))) unsigned int as1_uint;
typedef __attribute__((address_space(3))) unsigned int as3_uint;

__device__ __forceinline__ void gl_lds16(const void* g, void* l) {
  __builtin_amdgcn_global_load_lds((as1_uint*)g, (as3_uint*)l, 16, 0, 0);
}

// ---------------- f32 -> bf16 convert (8 elems/thread) ----------------
__global__ __launch_bounds__(256) void cvt_kernel(const float* __restrict__ in,
                                                  bf16_t* __restrict__ out) {
  size_t i = ((size_t)blockIdx.x * 256 + threadIdx.x) * 8;
  float4 a = *(const float4*)&in[i];
  float4 b = *(const float4*)&in[i + 4];
  bf16x8 o;
  o[0] = (bf16_t)a.x; o[1] = (bf16_t)a.y; o[2] = (bf16_t)a.z; o[3] = (bf16_t)a.w;
  o[4] = (bf16_t)b.x; o[5] = (bf16_t)b.y; o[6] = (bf16_t)b.z; o[7] = (bf16_t)b.w;
  *(bf16x8*)&out[i] = o;
}

// ---------------- transpose + cvt: in [R][C] f32 -> out [C][R] bf16 (64x64 tiles) ----------------
__global__ __launch_bounds__(256) void transpose_cvt_kernel(
    const float* __restrict__ in, bf16_t* __restrict__ out, int R, int C) {
  __shared__ float tile[64][65];
  const size_t matsz = (size_t)R * C;
  const float* inp = in + matsz * blockIdx.z;
  bf16_t* outp = out + matsz * blockIdx.z;
  int c0 = blockIdx.x * 64, r0 = blockIdx.y * 64;
  int t = threadIdx.x;
  int cq = (t & 15) * 4, rr = t >> 4;
#pragma unroll
  for (int i = 0; i < 4; ++i) {
    int r = rr + 16 * i;
    float4 v = *(const float4*)&inp[(size_t)(r0 + r) * C + c0 + cq];
    tile[r][cq] = v.x; tile[r][cq + 1] = v.y; tile[r][cq + 2] = v.z; tile[r][cq + 3] = v.w;
  }
  __syncthreads();
  int r8 = (t & 7) * 8, cc = t >> 3;
#pragma unroll
  for (int i = 0; i < 2; ++i) {
    int c = cc + 32 * i;
    bf16x8 o;
#pragma unroll
    for (int j = 0; j < 8; ++j) o[j] = (bf16_t)tile[r8 + j][c];
    *(bf16x8*)&outp[(size_t)(c0 + c) * R + r0 + r8] = o;
  }
}

// ---------------- gate: softmax(x @ gate_w) -> gate_t [E][B] f32 (transposed) ----------------
__global__ __launch_bounds__(256) void gate_kernel(
    const float* __restrict__ x, const float* __restrict__ gw, float* __restrict__ gate_t) {
  __shared__ float red[256][8];
  int b = blockIdx.x, t = threadIdx.x;
  float acc[8] = {0.f, 0.f, 0.f, 0.f, 0.f, 0.f, 0.f, 0.f};
  for (int d = t; d < D_DIM; d += 256) {
    float xv = x[(size_t)b * D_DIM + d];
#pragma unroll
    for (int e = 0; e < 8; ++e) acc[e] += xv * gw[d * 8 + e];
  }
#pragma unroll
  for (int e = 0; e < 8; ++e) red[t][e] = acc[e];
  __syncthreads();
  for (int s = 128; s > 0; s >>= 1) {
    if (t < s) {
#pragma unroll
      for (int e = 0; e < 8; ++e) red[t][e] += red[t + s][e];
    }
    __syncthreads();
  }
  if (t == 0) {
    float m = red[0][0];
#pragma unroll
    for (int e = 1; e < 8; ++e) m = fmaxf(m, red[0][e]);
    float p[8], sum = 0.f;
#pragma unroll
    for (int e = 0; e < 8; ++e) { p[e] = expf(red[0][e] - m); sum += p[e]; }
    float inv = 1.f / sum;
#pragma unroll
    for (int e = 0; e < 8; ++e) gate_t[e * B_DIM + b] = p[e] * inv;
  }
}

// ---------------- conn gate per expert ----------------
__global__ __launch_bounds__(256) void conn_kernel(
    const float* __restrict__ avg, const float* __restrict__ w1, const float* __restrict__ b1,
    const float* __restrict__ w2, const float* __restrict__ b2, const float* __restrict__ mask,
    float* __restrict__ conn) {
  __shared__ float red[256 * 32];
  __shared__ float h1[32];
  int e = blockIdx.x, t = threadIdx.x;
  float acc[32];
#pragma unroll
  for (int k = 0; k < 32; ++k) acc[k] = 0.f;
  for (int h = t; h < H_DIM; h += 256) {
    float av = avg[e * H_DIM + h];
    const float* w1p = &w1[((size_t)e * H_DIM + h) * 32];
#pragma unroll
    for (int k = 0; k < 32; ++k) acc[k] += av * w1p[k];
  }
#pragma unroll
  for (int k = 0; k < 32; ++k) red[t * 32 + k] = acc[k];
  __syncthreads();
  for (int s = 128; s > 0; s >>= 1) {
    if (t < s) {
#pragma unroll
      for (int k = 0; k < 32; ++k) red[t * 32 + k] += red[(t + s) * 32 + k];
    }
    __syncthreads();
  }
  if (t < 32) h1[t] = fmaxf(red[t] + b1[e * 32 + t], 0.f);
  __syncthreads();
  for (int h = t; h < H_DIM; h += 256) {
    float s = b2[e * H_DIM + h];
#pragma unroll
    for (int k = 0; k < 32; ++k) s += h1[k] * w2[((size_t)e * 32 + k) * H_DIM + h];
    conn[e * H_DIM + h] = (1.f / (1.f + expf(-s))) * mask[e * H_DIM + h];
  }
}

// ---------------- expert GEMM: 128x64 output tile, all 8 experts in registers, no atomics ----
// 8 waves (2m x 4n), each wave 64x16 per expert. A staged per k-step (reused by all e),
// B[e] streamed through an 8-slot LDS ring, depth-3 prefetch, counted vmcnt (T3/T4).
__global__ __launch_bounds__(512, 2) void expert_gemm(
    const bf16_t* __restrict__ A, const bf16_t* __restrict__ Bt,
    float* __restrict__ moe, bf16_t* __restrict__ moebf,
    const float* __restrict__ gate_t, const float* __restrict__ conn,
    const float* __restrict__ ebias) {
  __shared__ bf16_t As[2][128 * 64];   // 32 KB
  __shared__ bf16_t Bs[8][64 * 64];    // 64 KB

  // grid 256 = 8m x 32n, XCD swizzle: 32 contiguous wid per XCD (4 n-tiles, all m)
  const int wid = (blockIdx.x & 7) * 32 + (blockIdx.x >> 3);
  const int b0 = (wid & 7) * 128;
  const int n0 = (wid >> 3) * 64;

  const int t = threadIdx.x;
  const int lane = t & 63, wave = t >> 6;
  const int wmh = wave >> 2, wnq = wave & 3;
  const int lr = lane & 15, lk = (lane >> 4) * 8;
  const int csw = (lr & 7) << 3;
  const int srow = lane >> 3;
  const int scol = ((lane & 7) ^ srow) << 3;
  const size_t EB = (size_t)H_DIM * D_DIM;

  const bf16_t* Asrc = A + (size_t)(b0 + wave * 16 + srow) * D_DIM + scol;
  const bf16_t* Bsrc = Bt + (size_t)(n0 + wave * 8 + srow) * D_DIM + scol;

  auto stageA = [&](int buf, int kt) {
    gl_lds16(Asrc + (size_t)kt * 64, &As[buf][(wave * 16) * 64]);
    gl_lds16(Asrc + 8 * D_DIM + (size_t)kt * 64, &As[buf][(wave * 16 + 8) * 64]);
  };
  auto stageB = [&](int buf, int e, int kt) {
    gl_lds16(Bsrc + (size_t)e * EB + (size_t)kt * 64, &Bs[buf][(wave * 8) * 64]);
  };

  f32x4 acc[8][4];
#pragma unroll
  for (int e = 0; e < 8; ++e)
#pragma unroll
    for (int mf = 0; mf < 4; ++mf) acc[e][mf] = (f32x4){0.f, 0.f, 0.f, 0.f};

  // prologue: A(kt0) + B[0..2]
  stageA(0, 0);
  stageB(0, 0, 0);
  stageB(1, 1, 0);
  stageB(2, 2, 0);

  for (int kt = 0; kt < 16; ++kt) {
    const int ab = kt & 1;
    const bool nl = (kt < 15);
    bf16x8 af[2][4];
#pragma unroll
    for (int e = 0; e < 8; ++e) {
      // issue stage for flat-iter i+3
      if (e < 5) {
        stageB((e + 3) & 7, e + 3, kt);
        if (e == 4 && nl) stageA(ab ^ 1, kt + 1);
      } else if (nl) {
        stageB((e + 3) & 7, e - 5, kt + 1);
      }
      // counted wait: B[e] (and A(kt) transitively) arrived
      if (e < 4) {
        asm volatile("s_waitcnt vmcnt(3)" ::: "memory");
      } else if (nl) {
        asm volatile("s_waitcnt vmcnt(5)" ::: "memory");
      } else {
        if (e == 4) asm volatile("s_waitcnt vmcnt(3)" ::: "memory");
        if (e == 5) asm volatile("s_waitcnt vmcnt(2)" ::: "memory");
        if (e == 6) asm volatile("s_waitcnt vmcnt(1)" ::: "memory");
        if (e == 7) asm volatile("s_waitcnt vmcnt(0)" ::: "memory");
      }
      __builtin_amdgcn_s_barrier();
      __builtin_amdgcn_sched_barrier(0);
      if (e == 0) {
#pragma unroll
        for (int kk = 0; kk < 2; ++kk)
#pragma unroll
          for (int mf = 0; mf < 4; ++mf)
            af[kk][mf] = *(const bf16x8*)&As[ab][(wmh * 64 + mf * 16 + lr) * 64 +
                                                ((kk * 32 + lk) ^ csw)];
      }
      const bf16_t* Bb = &Bs[e][0];
      bf16x8 bf0 = *(const bf16x8*)&Bb[(wnq * 16 + lr) * 64 + (lk ^ csw)];
      bf16x8 bf1 = *(const bf16x8*)&Bb[(wnq * 16 + lr) * 64 + ((32 + lk) ^ csw)];
      __builtin_amdgcn_s_setprio(1);
#pragma unroll
      for (int mf = 0; mf < 4; ++mf) {
        acc[e][mf] = __builtin_amdgcn_mfma_f32_16x16x32_bf16(af[0][mf], bf0, acc[e][mf], 0, 0, 0);
        acc[e][mf] = __builtin_amdgcn_mfma_f32_16x16x32_bf16(af[1][mf], bf1, acc[e][mf], 0, 0, 0);
      }
      __builtin_amdgcn_s_setprio(0);
      __builtin_amdgcn_sched_barrier(0);
    }
  }

  // epilogue: per-expert gate/conn/bias/relu, register sum over e, single store
  const int r4 = (lane >> 4) * 4;
  const int gcol = n0 + wnq * 16 + lr;
  const int growb = b0 + wmh * 64;
  f32x4 sum[4];
#pragma unroll
  for (int mf = 0; mf < 4; ++mf) sum[mf] = (f32x4){0.f, 0.f, 0.f, 0.f};
#pragma unroll
  for (int e = 0; e < 8; ++e) {
    const float cm = conn[e * H_DIM + gcol];
    const float bb = ebias[e * H_DIM + gcol];
#pragma unroll
    for (int mf = 0; mf < 4; ++mf) {
      const float4 g4 = *(const float4*)&gate_t[e * B_DIM + growb + mf * 16 + r4];
      sum[mf][0] += fmaxf((acc[e][mf][0] + bb) * cm, 0.f) * g4.x;
      sum[mf][1] += fmaxf((acc[e][mf][1] + bb) * cm, 0.f) * g4.y;
      sum[mf][2] += fmaxf((acc[e][mf][2] + bb) * cm, 0.f) * g4.z;
      sum[mf][3] += fmaxf((acc[e][mf][3] + bb) * cm, 0.f) * g4.w;
    }
  }
#pragma unroll
  for (int mf = 0; mf < 4; ++mf)
#pragma unroll
    for (int j = 0; j < 4; ++j) {
      const int grow = growb + mf * 16 + r4 + j;
      moe[(size_t)grow * H_DIM + gcol] = sum[mf][j];
      moebf[(size_t)grow * H_DIM + gcol] = (bf16_t)sum[mf][j];
    }
}

// ---------------- stage-2 GEMM: 128x128 tile, split-K x4, plain stores to partials ----------
__global__ __launch_bounds__(256, 2) void gemm_sk4(
    const bf16_t* __restrict__ A, const bf16_t* __restrict__ Bt, float* __restrict__ C) {
  __shared__ bf16_t As[2][128 * 64];
  __shared__ bf16_t Bs[2][128 * 64];

  const int wid = (blockIdx.x & 7) * 64 + (blockIdx.x >> 3);
  const int ez = wid >> 7;          // split-K part 0..3
  const int rem = wid & 127;
  const int b0 = (rem & 7) * 128;
  const int n0 = (rem >> 3) * 128;
  const int kbase = ez << 9;        // *512

  const int t = threadIdx.x;
  const int lane = t & 63, wave = t >> 6;
  const int wm = wave >> 1, wn = wave & 1;
  const int lr = lane & 15, lk = (lane >> 4) * 8;
  const int csw = (lr & 7) << 3;
  const int srow = lane >> 3;
  const int scol = ((lane & 7) ^ srow) << 3;

  const bf16_t* Arow = A + (size_t)(b0 + srow) * 2048 + kbase + scol;
  const bf16_t* Brow = Bt + (size_t)(n0 + srow) * 2048 + kbase + scol;

  const f32x4 zv = {0.f, 0.f, 0.f, 0.f};
  f32x4 acc[4][4];
#pragma unroll
  for (int mf = 0; mf < 4; ++mf)
#pragma unroll
    for (int nf = 0; nf < 4; ++nf) acc[mf][nf] = zv;

  auto STAGE = [&](int bsel, int kt) {
    const int ko = kt << 6;
#pragma unroll
    for (int i = 0; i < 4; ++i) {
      int rb = i * 32 + wave * 8;
      gl_lds16(Arow + (size_t)rb * 2048 + ko, &As[bsel][rb * 64]);
      gl_lds16(Brow + (size_t)rb * 2048 + ko, &Bs[bsel][rb * 64]);
    }
  };

  auto COMPUTE = [&](int bsel) {
    bf16x8 bfr[2][4];
#pragma unroll
    for (int kk = 0; kk < 2; ++kk)
#pragma unroll
      for (int nf = 0; nf < 4; ++nf)
        bfr[kk][nf] = *(const bf16x8*)&Bs[bsel][(wn * 64 + nf * 16 + lr) * 64 + ((kk * 32 + lk) ^ csw)];
    __builtin_amdgcn_s_setprio(1);
#pragma unroll
    for (int mf = 0; mf < 4; ++mf) {
      bf16x8 a0 = *(const bf16x8*)&As[bsel][(wm * 64 + mf * 16 + lr) * 64 + (lk ^ csw)];
      bf16x8 a1 = *(const bf16x8*)&As[bsel][(wm * 64 + mf * 16 + lr) * 64 + ((32 + lk) ^ csw)];
#pragma unroll
      for (int nf = 0; nf < 4; ++nf)
        acc[mf][nf] = __builtin_amdgcn_mfma_f32_16x16x32_bf16(a0, bfr[0][nf], acc[mf][nf], 0, 0, 0);
#pragma unroll
      for (int nf = 0; nf < 4; ++nf)
        acc[mf][nf] = __builtin_amdgcn_mfma_f32_16x16x32_bf16(a1, bfr[1][nf], acc[mf][nf], 0, 0, 0);
    }
    __builtin_amdgcn_s_setprio(0);
  };

  STAGE(0, 0);
  __syncthreads();
  for (int kt = 0; kt < 7; ++kt) {
    STAGE((kt + 1) & 1, kt + 1);
    COMPUTE(kt & 1);
    __syncthreads();
  }
  COMPUTE(1);

  const int r4 = (lane >> 4) * 4;
#pragma unroll
  for (int mf = 0; mf < 4; ++mf) {
#pragma unroll
    for (int nf = 0; nf < 4; ++nf) {
      int gcol = n0 + wn * 64 + nf * 16 + lr;
#pragma unroll
      for (int j = 0; j < 4; ++j) {
        int grow = b0 + wm * 64 + mf * 16 + r4 + j;
        C[((size_t)ez * B_DIM + grow) * 2048 + gcol] = acc[mf][nf][j];
      }
    }
  }
}

// ---------------- softmax over M: sum 4 split-K partials + bias -> bf16 attn ----------------
__global__ __launch_bounds__(256) void softmax_kernel(
    const float* __restrict__ lg, const float* __restrict__ bias, bf16_t* __restrict__ attn) {
  const size_t P = (size_t)B_DIM * M_DIM;
  int b = blockIdx.x, t = threadIdx.x;
  int lane = t & 63, wave = t >> 6;
  __shared__ float rmax[4], rsum[4];
  float v[8];
  float m = -1e30f;
#pragma unroll
  for (int i = 0; i < 8; ++i) {
    size_t idx = (size_t)b * M_DIM + i * 256 + t;
    v[i] = lg[idx] + lg[P + idx] + lg[2 * P + idx] + lg[3 * P + idx] + bias[i * 256 + t];
    m = fmaxf(m, v[i]);
  }
#pragma unroll
  for (int off = 32; off >= 1; off >>= 1) m = fmaxf(m, __shfl_xor(m, off));
  if (lane == 0) rmax[wave] = m;
  __syncthreads();
  m = fmaxf(fmaxf(rmax[0], rmax[1]), fmaxf(rmax[2], rmax[3]));
  float s = 0.f;
#pragma unroll
  for (int i = 0; i < 8; ++i) {
    v[i] = __expf(v[i] - m);
    s += v[i];
  }
#pragma unroll
  for (int off = 32; off >= 1; off >>= 1) s += __shfl_xor(s, off);
  if (lane == 0) rsum[wave] = s;
  __syncthreads();
  s = rsum[0] + rsum[1] + rsum[2] + rsum[3];
  float inv = 1.f / s;
#pragma unroll
  for (int i = 0; i < 8; ++i) attn[(size_t)b * M_DIM + i * 256 + t] = (bf16_t)(v[i] * inv);
}

// ---------------- final blended activation: out = act(out + sum of 4 readv partials) --------
__global__ __launch_bounds__(256) void act_kernel(
    const float* __restrict__ rdv, const float* __restrict__ aw, float* __restrict__ out) {
  const size_t P = (size_t)B_DIM * H_DIM;
  int i = blockIdx.x * 256 + threadIdx.x;
  float w[9], m = -1e30f;
#pragma unroll
  for (int j = 0; j < 9; ++j) { w[j] = aw[j]; m = fmaxf(m, w[j]); }
  float p[9], s = 0.f;
#pragma unroll
  for (int j = 0; j < 9; ++j) { p[j] = expf(w[j] - m); s += p[j]; }
  float inv = 1.f / s;
#pragma unroll
  for (int j = 0; j < 9; ++j) p[j] *= inv;
  float4 mv = ((const float4*)out)[i];
  float4 r0 = ((const float4*)rdv)[i];
  float4 r1 = ((const float4*)(rdv + P))[i];
  float4 r2 = ((const float4*)(rdv + 2 * P))[i];
  float4 r3 = ((const float4*)(rdv + 3 * P))[i];
  float xs[4] = {mv.x + r0.x + r1.x + r2.x + r3.x, mv.y + r0.y + r1.y + r2.y + r3.y,
                 mv.z + r0.z + r1.z + r2.z + r3.z, mv.w + r0.w + r1.w + r2.w + r3.w};
  float os[4];
#pragma unroll
  for (int q = 0; q < 4; ++q) {
    float xv = xs[q];
    float enx = expf(-xv);
    float ex = expf(xv);
    float sig = 1.f / (1.f + enx);
    float em1 = expm1f(xv);
    float th = tanhf(xv);
    float rl = fmaxf(xv, 0.f);
    float si = xv * sig;
    float ge = 0.5f * xv * (1.f + erff(xv * 0.70710678118654752f));
    float se = 1.0507009873554805f * (xv > 0.f ? xv : 1.6732632423543772f * em1);
    float el = xv > 0.f ? xv : em1;
    float sp = log1pf(ex);
    float mi = xv * tanhf(sp);
    os[q] = p[0] * sig + p[1] * el + p[2] * th + p[3] * rl + p[4] * si + p[5] * ge + p[6] * se + p[7] * mi;
  }
  ((float4*)out)[i] = make_float4(os[0], os[1], os[2], os[3]);
}

extern "C" void kernel_launch(void* const* d_in, const int* in_sizes, int n_in,
                              void* d_out, int out_size, void* d_ws, size_t ws_size,
                              hipStream_t stream) {
  const float* x        = (const float*)d_in[0];
  const float* gate_w   = (const float*)d_in[1];
  const float* expert_w = (const float*)d_in[2];
  const float* expert_b = (const float*)d_in[3];
  const float* conn_w1  = (const float*)d_in[4];
  const float* conn_b1  = (const float*)d_in[5];
  const float* conn_w2  = (const float*)d_in[6];
  const float* conn_b2  = (const float*)d_in[7];
  const float* navg     = (const float*)d_in[8];
  const float* nmask    = (const float*)d_in[9];
  const float* mem_rw   = (const float*)d_in[10];
  const float* mem_rb   = (const float*)d_in[11];
  const float* memory   = (const float*)d_in[12];
  const float* act_w    = (const float*)d_in[13];
  float* out = (float*)d_out;

  char* ws = (char*)d_ws;
  // persistent-within-call buffers
  bf16_t* wbT    = (bf16_t*)(ws + 0);            // [E][H][D] 33554432
  bf16_t* mrT    = (bf16_t*)(ws + 33554432);     // [M][H] 8388608
  bf16_t* memT   = (bf16_t*)(ws + 41943040);     // [H][M] 8388608
  float*  gate_t = (float*)(ws + 50331648);      // [E][B] 32768
  float*  connb  = (float*)(ws + 50364416);      // [E][H] 65536
  bf16_t* x_bf   = (bf16_t*)(ws + 50429952);     // 2097152 (ends 52527104)
  bf16_t* moe_bf = (bf16_t*)(ws + 52527104);     // 4194304 (ends 56721408)
  // aliases (regions dead by the time these are written)
  float*  logits = (float*)(ws + 0);             // [4][B][M] 33554432 (wbT dead)
  bf16_t* attn   = (bf16_t*)(ws + 33554432);     // 4194304 (mrT dead after logits gemm)
  float*  readv  = (float*)(ws + 0);             // [4][B][H] 33554432 (logits dead)
  float*  moe    = out;                          // [B][H] f32 lives in d_out

  // 1. one-time conversions / transposes
  cvt_kernel<<<dim3(512), 256, 0, stream>>>(x, x_bf);
  transpose_cvt_kernel<<<dim3(32, 16, 8), 256, 0, stream>>>(expert_w, wbT, D_DIM, H_DIM);
  transpose_cvt_kernel<<<dim3(32, 32, 1), 256, 0, stream>>>(mem_rw, mrT, H_DIM, M_DIM);
  transpose_cvt_kernel<<<dim3(32, 32, 1), 256, 0, stream>>>(memory, memT, M_DIM, H_DIM);
  // 2. gate + conn
  gate_kernel<<<dim3(B_DIM), 256, 0, stream>>>(x, gate_w, gate_t);
  conn_kernel<<<dim3(E_DIM), 256, 0, stream>>>(navg, conn_w1, conn_b1, conn_w2, conn_b2, nmask, connb);
  // 3. expert GEMM, all experts in registers, writes moe (f32, d_out) + moe_bf
  expert_gemm<<<dim3(256), 512, 0, stream>>>(x_bf, wbT, moe, moe_bf, gate_t, connb, expert_b);
  // 4. memory attention: split-K4 GEMM -> partials, fused sums downstream
  gemm_sk4<<<dim3(512), 256, 0, stream>>>(moe_bf, mrT, logits);
  softmax_kernel<<<dim3(B_DIM), 256, 0, stream>>>(logits, mem_rb, attn);
  gemm_sk4<<<dim3(512), 256, 0, stream>>>(attn, memT, readv);
  // 5. blended activation (in-place on d_out)
  act_kernel<<<dim3((B_DIM * H_DIM) / (256 * 4)), 256, 0, stream>>>(readv, act_w, out);
}

// Round 5
// 146.837 us; speedup vs baseline: 2.3556x; 1.1123x over previous
//
#include <hip/hip_runtime.h>
#include <hip/hip_bf16.h>
#include <math.h>

typedef __bf16 bf16_t;
typedef __bf16 bf16x8 __attribute__((ext_vector_type(8)));
typedef float f32x4 __attribute__((ext_vector_type(4)));

#define B_DIM 1024
#define D_DIM 1024
#define H_DIM 2048
#define E_DIM 8
#define M_DIM 2048

typedef const __attribute__((address_space(1))) unsigned int as1_uint;
typedef __attribute__((address_space(3))) unsigned int as3_uint;

__device__ __forceinline__ void gl_lds16(const void* g, void* l) {
  __builtin_amdgcn_global_load_lds((as1_uint*)g, (as3_uint*)l, 16, 0, 0);
}

// ---------------- f32 -> bf16 convert (8 elems/thread) ----------------
__global__ __launch_bounds__(256) void cvt_kernel(const float* __restrict__ in,
                                                  bf16_t* __restrict__ out) {
  size_t i = ((size_t)blockIdx.x * 256 + threadIdx.x) * 8;
  float4 a = *(const float4*)&in[i];
  float4 b = *(const float4*)&in[i + 4];
  bf16x8 o;
  o[0] = (bf16_t)a.x; o[1] = (bf16_t)a.y; o[2] = (bf16_t)a.z; o[3] = (bf16_t)a.w;
  o[4] = (bf16_t)b.x; o[5] = (bf16_t)b.y; o[6] = (bf16_t)b.z; o[7] = (bf16_t)b.w;
  *(bf16x8*)&out[i] = o;
}

// ---------------- merged transpose + cvt: z<8 expert_w slab, z=8 mem_rw, z=9 memory --------
__global__ __launch_bounds__(256) void transpose_all(
    const float* __restrict__ ew, const float* __restrict__ mrw, const float* __restrict__ mem,
    bf16_t* __restrict__ wbT, bf16_t* __restrict__ mrT, bf16_t* __restrict__ memT) {
  __shared__ float tile[64][65];
  const int z = blockIdx.z;
  const float* in; bf16_t* out; int R, C;
  if (z < 8) {
    if (blockIdx.y >= 16) return;
    in = ew + (size_t)z * D_DIM * H_DIM; out = wbT + (size_t)z * D_DIM * H_DIM;
    R = D_DIM; C = H_DIM;
  } else if (z == 8) {
    in = mrw; out = mrT; R = H_DIM; C = M_DIM;
  } else {
    in = mem; out = memT; R = M_DIM; C = H_DIM;
  }
  int c0 = blockIdx.x * 64, r0 = blockIdx.y * 64;
  int t = threadIdx.x;
  int cq = (t & 15) * 4, rr = t >> 4;
#pragma unroll
  for (int i = 0; i < 4; ++i) {
    int r = rr + 16 * i;
    float4 v = *(const float4*)&in[(size_t)(r0 + r) * C + c0 + cq];
    tile[r][cq] = v.x; tile[r][cq + 1] = v.y; tile[r][cq + 2] = v.z; tile[r][cq + 3] = v.w;
  }
  __syncthreads();
  int r8 = (t & 7) * 8, cc = t >> 3;
#pragma unroll
  for (int i = 0; i < 2; ++i) {
    int c = cc + 32 * i;
    bf16x8 o;
#pragma unroll
    for (int j = 0; j < 8; ++j) o[j] = (bf16_t)tile[r8 + j][c];
    *(bf16x8*)&out[(size_t)(c0 + c) * R + r0 + r8] = o;
  }
}

// ---------------- gate: softmax(x @ gate_w) -> gate_t [E][B] f32 ----------------
__global__ __launch_bounds__(256) void gate_kernel(
    const float* __restrict__ x, const float* __restrict__ gw, float* __restrict__ gate_t) {
  __shared__ float red[256][8];
  int b = blockIdx.x, t = threadIdx.x;
  float acc[8] = {0.f, 0.f, 0.f, 0.f, 0.f, 0.f, 0.f, 0.f};
  for (int d = t; d < D_DIM; d += 256) {
    float xv = x[(size_t)b * D_DIM + d];
#pragma unroll
    for (int e = 0; e < 8; ++e) acc[e] += xv * gw[d * 8 + e];
  }
#pragma unroll
  for (int e = 0; e < 8; ++e) red[t][e] = acc[e];
  __syncthreads();
  for (int s = 128; s > 0; s >>= 1) {
    if (t < s) {
#pragma unroll
      for (int e = 0; e < 8; ++e) red[t][e] += red[t + s][e];
    }
    __syncthreads();
  }
  if (t == 0) {
    float m = red[0][0];
#pragma unroll
    for (int e = 1; e < 8; ++e) m = fmaxf(m, red[0][e]);
    float p[8], sum = 0.f;
#pragma unroll
    for (int e = 0; e < 8; ++e) { p[e] = expf(red[0][e] - m); sum += p[e]; }
    float inv = 1.f / sum;
#pragma unroll
    for (int e = 0; e < 8; ++e) gate_t[e * B_DIM + b] = p[e] * inv;
  }
}

// ---------------- conn part 1: per-(e,chunk) partial reduce -> h1p [E][8][32] ----------------
__global__ __launch_bounds__(256) void conn1_kernel(
    const float* __restrict__ avg, const float* __restrict__ w1, float* __restrict__ h1p) {
  __shared__ float red[256 * 32];
  int e = blockIdx.x >> 3, c = blockIdx.x & 7, t = threadIdx.x;
  int h = c * 256 + t;
  float av = avg[e * H_DIM + h];
  const float* w1p = &w1[((size_t)e * H_DIM + h) * 32];
#pragma unroll
  for (int k = 0; k < 32; ++k) red[t * 32 + k] = av * w1p[k];
  __syncthreads();
  for (int s = 128; s > 0; s >>= 1) {
    if (t < s) {
#pragma unroll
      for (int k = 0; k < 32; ++k) red[t * 32 + k] += red[(t + s) * 32 + k];
    }
    __syncthreads();
  }
  if (t < 32) h1p[(e * 8 + c) * 32 + t] = red[t];
}

// ---------------- conn part 2: sum partials, relu, sigmoid map -> conn [E][H] ----------------
__global__ __launch_bounds__(256) void conn2_kernel(
    const float* __restrict__ h1p, const float* __restrict__ b1,
    const float* __restrict__ w2, const float* __restrict__ b2,
    const float* __restrict__ mask, float* __restrict__ conn) {
  __shared__ float h1[32];
  int e = blockIdx.x >> 3, c = blockIdx.x & 7, t = threadIdx.x;
  if (t < 32) {
    float s = 0.f;
#pragma unroll
    for (int c2 = 0; c2 < 8; ++c2) s += h1p[(e * 8 + c2) * 32 + t];
    h1[t] = fmaxf(s + b1[e * 32 + t], 0.f);
  }
  __syncthreads();
  int h = c * 256 + t;
  float s = b2[e * H_DIM + h];
#pragma unroll
  for (int k = 0; k < 32; ++k) s += h1[k] * w2[((size_t)e * 32 + k) * H_DIM + h];
  conn[e * H_DIM + h] = (1.f / (1.f + expf(-s))) * mask[e * H_DIM + h];
}

// ---------------- expert GEMM: 128x64 tile, 8 experts in registers, depth-5 B prefetch ------
__global__ __launch_bounds__(512, 2) void expert_gemm(
    const bf16_t* __restrict__ A, const bf16_t* __restrict__ Bt,
    float* __restrict__ moe, bf16_t* __restrict__ moebf,
    const float* __restrict__ gate_t, const float* __restrict__ conn,
    const float* __restrict__ ebias) {
  __shared__ bf16_t As[2][128 * 64];   // 32 KB
  __shared__ bf16_t Bs[8][64 * 64];    // 64 KB

  const int wid = (blockIdx.x & 7) * 32 + (blockIdx.x >> 3);
  const int b0 = (wid & 7) * 128;
  const int n0 = (wid >> 3) * 64;

  const int t = threadIdx.x;
  const int lane = t & 63, wave = t >> 6;
  const int wmh = wave >> 2, wnq = wave & 3;
  const int lr = lane & 15, lk = (lane >> 4) * 8;
  const int csw = (lr & 7) << 3;
  const int srow = lane >> 3;
  const int scol = ((lane & 7) ^ srow) << 3;
  const size_t EB = (size_t)H_DIM * D_DIM;

  const bf16_t* Asrc = A + (size_t)(b0 + wave * 16 + srow) * D_DIM + scol;
  const bf16_t* Bsrc = Bt + (size_t)(n0 + wave * 8 + srow) * D_DIM + scol;

  auto stageA = [&](int buf, int kt) {
    gl_lds16(Asrc + (size_t)kt * 64, &As[buf][(wave * 16) * 64]);
    gl_lds16(Asrc + 8 * D_DIM + (size_t)kt * 64, &As[buf][(wave * 16 + 8) * 64]);
  };
  auto stageB = [&](int buf, int e, int kt) {
    gl_lds16(Bsrc + (size_t)e * EB + (size_t)kt * 64, &Bs[buf][(wave * 8) * 64]);
  };

  f32x4 acc[8][4];
#pragma unroll
  for (int e = 0; e < 8; ++e)
#pragma unroll
    for (int mf = 0; mf < 4; ++mf) acc[e][mf] = (f32x4){0.f, 0.f, 0.f, 0.f};

  // prologue: A(0) + B experts 0..4 of kt 0 (depth-5)
  stageA(0, 0);
#pragma unroll
  for (int s = 0; s < 5; ++s) stageB(s, s, 0);

  for (int kt = 0; kt < 16; ++kt) {
    const int ab = kt & 1;
    const bool nl = (kt < 15);
    bf16x8 af[2][4];
#pragma unroll
    for (int e = 0; e < 8; ++e) {
      // issue prefetch for flat phase +5 (slot == expert index == (e+5)&7)
      if (e < 3) {
        stageB((e + 5) & 7, (e + 5) & 7, kt);
      } else if (nl) {
        stageB((e + 5) & 7, (e + 5) & 7, kt + 1);
        if (e == 3) stageA(ab ^ 1, kt + 1);
      }
      // counted waits (ledger: B in flight = 5; +2 A-loads outstanding for e>=3)
      if (e < 3) {
        asm volatile("s_waitcnt vmcnt(5)" ::: "memory");
      } else if (nl) {
        asm volatile("s_waitcnt vmcnt(7)" ::: "memory");
      } else {
        if (e == 3) asm volatile("s_waitcnt vmcnt(4)" ::: "memory");
        if (e == 4) asm volatile("s_waitcnt vmcnt(3)" ::: "memory");
        if (e == 5) asm volatile("s_waitcnt vmcnt(2)" ::: "memory");
        if (e == 6) asm volatile("s_waitcnt vmcnt(1)" ::: "memory");
        if (e == 7) asm volatile("s_waitcnt vmcnt(0)" ::: "memory");
      }
      __builtin_amdgcn_s_barrier();
      __builtin_amdgcn_sched_barrier(0);
      if (e == 0) {
#pragma unroll
        for (int kk = 0; kk < 2; ++kk)
#pragma unroll
          for (int mf = 0; mf < 4; ++mf)
            af[kk][mf] = *(const bf16x8*)&As[ab][(wmh * 64 + mf * 16 + lr) * 64 +
                                                ((kk * 32 + lk) ^ csw)];
      }
      const bf16_t* Bb = &Bs[e][0];
      bf16x8 bf0 = *(const bf16x8*)&Bb[(wnq * 16 + lr) * 64 + (lk ^ csw)];
      bf16x8 bf1 = *(const bf16x8*)&Bb[(wnq * 16 + lr) * 64 + ((32 + lk) ^ csw)];
      __builtin_amdgcn_s_setprio(1);
#pragma unroll
      for (int mf = 0; mf < 4; ++mf) {
        acc[e][mf] = __builtin_amdgcn_mfma_f32_16x16x32_bf16(af[0][mf], bf0, acc[e][mf], 0, 0, 0);
        acc[e][mf] = __builtin_amdgcn_mfma_f32_16x16x32_bf16(af[1][mf], bf1, acc[e][mf], 0, 0, 0);
      }
      __builtin_amdgcn_s_setprio(0);
      __builtin_amdgcn_sched_barrier(0);
    }
  }

  // epilogue: per-expert gate/conn/bias/relu, register sum over e, single store
  const int r4 = (lane >> 4) * 4;
  const int gcol = n0 + wnq * 16 + lr;
  const int growb = b0 + wmh * 64;
  f32x4 sum[4];
#pragma unroll
  for (int mf = 0; mf < 4; ++mf) sum[mf] = (f32x4){0.f, 0.f, 0.f, 0.f};
#pragma unroll
  for (int e = 0; e < 8; ++e) {
    const float cm = conn[e * H_DIM + gcol];
    const float bb = ebias[e * H_DIM + gcol];
#pragma unroll
    for (int mf = 0; mf < 4; ++mf) {
      const float4 g4 = *(const float4*)&gate_t[e * B_DIM + growb + mf * 16 + r4];
      sum[mf][0] += fmaxf((acc[e][mf][0] + bb) * cm, 0.f) * g4.x;
      sum[mf][1] += fmaxf((acc[e][mf][1] + bb) * cm, 0.f) * g4.y;
      sum[mf][2] += fmaxf((acc[e][mf][2] + bb) * cm, 0.f) * g4.z;
      sum[mf][3] += fmaxf((acc[e][mf][3] + bb) * cm, 0.f) * g4.w;
    }
  }
#pragma unroll
  for (int mf = 0; mf < 4; ++mf)
#pragma unroll
    for (int j = 0; j < 4; ++j) {
      const int grow = growb + mf * 16 + r4 + j;
      moe[(size_t)grow * H_DIM + gcol] = sum[mf][j];
      moebf[(size_t)grow * H_DIM + gcol] = (bf16_t)sum[mf][j];
    }
}

// ---------------- stage-2 GEMM: 128x128 tile, split-K x2, plain stores to partials ----------
__global__ __launch_bounds__(256, 2) void gemm_sk2(
    const bf16_t* __restrict__ A, const bf16_t* __restrict__ Bt, float* __restrict__ C) {
  __shared__ bf16_t As[2][128 * 64];
  __shared__ bf16_t Bs[2][128 * 64];

  const int wid = (blockIdx.x & 7) * 32 + (blockIdx.x >> 3);
  const int ez = wid >> 7;          // split-K half 0..1
  const int rem = wid & 127;
  const int b0 = (rem & 7) * 128;
  const int n0 = (rem >> 3) * 128;
  const int kbase = ez << 10;       // *1024

  const int t = threadIdx.x;
  const int lane = t & 63, wave = t >> 6;
  const int wm = wave >> 1, wn = wave & 1;
  const int lr = lane & 15, lk = (lane >> 4) * 8;
  const int csw = (lr & 7) << 3;
  const int srow = lane >> 3;
  const int scol = ((lane & 7) ^ srow) << 3;

  const bf16_t* Arow = A + (size_t)(b0 + srow) * 2048 + kbase + scol;
  const bf16_t* Brow = Bt + (size_t)(n0 + srow) * 2048 + kbase + scol;

  const f32x4 zv = {0.f, 0.f, 0.f, 0.f};
  f32x4 acc[4][4];
#pragma unroll
  for (int mf = 0; mf < 4; ++mf)
#pragma unroll
    for (int nf = 0; nf < 4; ++nf) acc[mf][nf] = zv;

  auto STAGE = [&](int bsel, int kt) {
    const int ko = kt << 6;
#pragma unroll
    for (int i = 0; i < 4; ++i) {
      int rb = i * 32 + wave * 8;
      gl_lds16(Arow + (size_t)rb * 2048 + ko, &As[bsel][rb * 64]);
      gl_lds16(Brow + (size_t)rb * 2048 + ko, &Bs[bsel][rb * 64]);
    }
  };

  auto COMPUTE = [&](int bsel) {
    bf16x8 bfr[2][4];
#pragma unroll
    for (int kk = 0; kk < 2; ++kk)
#pragma unroll
      for (int nf = 0; nf < 4; ++nf)
        bfr[kk][nf] = *(const bf16x8*)&Bs[bsel][(wn * 64 + nf * 16 + lr) * 64 + ((kk * 32 + lk) ^ csw)];
    __builtin_amdgcn_s_setprio(1);
#pragma unroll
    for (int mf = 0; mf < 4; ++mf) {
      bf16x8 a0 = *(const bf16x8*)&As[bsel][(wm * 64 + mf * 16 + lr) * 64 + (lk ^ csw)];
      bf16x8 a1 = *(const bf16x8*)&As[bsel][(wm * 64 + mf * 16 + lr) * 64 + ((32 + lk) ^ csw)];
#pragma unroll
      for (int nf = 0; nf < 4; ++nf)
        acc[mf][nf] = __builtin_amdgcn_mfma_f32_16x16x32_bf16(a0, bfr[0][nf], acc[mf][nf], 0, 0, 0);
#pragma unroll
      for (int nf = 0; nf < 4; ++nf)
        acc[mf][nf] = __builtin_amdgcn_mfma_f32_16x16x32_bf16(a1, bfr[1][nf], acc[mf][nf], 0, 0, 0);
    }
    __builtin_amdgcn_s_setprio(0);
  };

  STAGE(0, 0);
  __syncthreads();
  for (int kt = 0; kt < 15; ++kt) {
    STAGE((kt + 1) & 1, kt + 1);
    COMPUTE(kt & 1);
    __syncthreads();
  }
  COMPUTE(1);

  const int r4 = (lane >> 4) * 4;
#pragma unroll
  for (int mf = 0; mf < 4; ++mf) {
#pragma unroll
    for (int nf = 0; nf < 4; ++nf) {
      int gcol = n0 + wn * 64 + nf * 16 + lr;
#pragma unroll
      for (int j = 0; j < 4; ++j) {
        int grow = b0 + wm * 64 + mf * 16 + r4 + j;
        C[((size_t)ez * B_DIM + grow) * 2048 + gcol] = acc[mf][nf][j];
      }
    }
  }
}

// ---------------- softmax over M: sum 2 split-K partials + bias -> bf16 attn ----------------
__global__ __launch_bounds__(256) void softmax_kernel(
    const float* __restrict__ lg, const float* __restrict__ bias, bf16_t* __restrict__ attn) {
  const size_t P = (size_t)B_DIM * M_DIM;
  int b = blockIdx.x, t = threadIdx.x;
  int lane = t & 63, wave = t >> 6;
  __shared__ float rmax[4], rsum[4];
  float v[8];
  float m = -1e30f;
#pragma unroll
  for (int i = 0; i < 8; ++i) {
    size_t idx = (size_t)b * M_DIM + i * 256 + t;
    v[i] = lg[idx] + lg[P + idx] + bias[i * 256 + t];
    m = fmaxf(m, v[i]);
  }
#pragma unroll
  for (int off = 32; off >= 1; off >>= 1) m = fmaxf(m, __shfl_xor(m, off));
  if (lane == 0) rmax[wave] = m;
  __syncthreads();
  m = fmaxf(fmaxf(rmax[0], rmax[1]), fmaxf(rmax[2], rmax[3]));
  float s = 0.f;
#pragma unroll
  for (int i = 0; i < 8; ++i) {
    v[i] = __expf(v[i] - m);
    s += v[i];
  }
#pragma unroll
  for (int off = 32; off >= 1; off >>= 1) s += __shfl_xor(s, off);
  if (lane == 0) rsum[wave] = s;
  __syncthreads();
  s = rsum[0] + rsum[1] + rsum[2] + rsum[3];
  float inv = 1.f / s;
#pragma unroll
  for (int i = 0; i < 8; ++i) attn[(size_t)b * M_DIM + i * 256 + t] = (bf16_t)(v[i] * inv);
}

// ---------------- final blended activation: out = act(out + sum of 2 readv partials) --------
__global__ __launch_bounds__(256) void act_kernel(
    const float* __restrict__ rdv, const float* __restrict__ aw, float* __restrict__ out) {
  const size_t P = (size_t)B_DIM * H_DIM;
  int i = blockIdx.x * 256 + threadIdx.x;
  float w[9], m = -1e30f;
#pragma unroll
  for (int j = 0; j < 9; ++j) { w[j] = aw[j]; m = fmaxf(m, w[j]); }
  float p[9], s = 0.f;
#pragma unroll
  for (int j = 0; j < 9; ++j) { p[j] = expf(w[j] - m); s += p[j]; }
  float inv = 1.f / s;
#pragma unroll
  for (int j = 0; j < 9; ++j) p[j] *= inv;
  float4 mv = ((const float4*)out)[i];
  float4 r0 = ((const float4*)rdv)[i];
  float4 r1 = ((const float4*)(rdv + P))[i];
  float xs[4] = {mv.x + r0.x + r1.x, mv.y + r0.y + r1.y,
                 mv.z + r0.z + r1.z, mv.w + r0.w + r1.w};
  float os[4];
#pragma unroll
  for (int q = 0; q < 4; ++q) {
    float xv = xs[q];
    float enx = expf(-xv);
    float ex = expf(xv);
    float sig = 1.f / (1.f + enx);
    float em1 = expm1f(xv);
    float th = tanhf(xv);
    float rl = fmaxf(xv, 0.f);
    float si = xv * sig;
    float ge = 0.5f * xv * (1.f + erff(xv * 0.70710678118654752f));
    float se = 1.0507009873554805f * (xv > 0.f ? xv : 1.6732632423543772f * em1);
    float el = xv > 0.f ? xv : em1;
    float sp = log1pf(ex);
    float mi = xv * tanhf(sp);
    os[q] = p[0] * sig + p[1] * el + p[2] * th + p[3] * rl + p[4] * si + p[5] * ge + p[6] * se + p[7] * mi;
  }
  ((float4*)out)[i] = make_float4(os[0], os[1], os[2], os[3]);
}

extern "C" void kernel_launch(void* const* d_in, const int* in_sizes, int n_in,
                              void* d_out, int out_size, void* d_ws, size_t ws_size,
                              hipStream_t stream) {
  const float* x        = (const float*)d_in[0];
  const float* gate_w   = (const float*)d_in[1];
  const float* expert_w = (const float*)d_in[2];
  const float* expert_b = (const float*)d_in[3];
  const float* conn_w1  = (const float*)d_in[4];
  const float* conn_b1  = (const float*)d_in[5];
  const float* conn_w2  = (const float*)d_in[6];
  const float* conn_b2  = (const float*)d_in[7];
  const float* navg     = (const float*)d_in[8];
  const float* nmask    = (const float*)d_in[9];
  const float* mem_rw   = (const float*)d_in[10];
  const float* mem_rb   = (const float*)d_in[11];
  const float* memory   = (const float*)d_in[12];
  const float* act_w    = (const float*)d_in[13];
  float* out = (float*)d_out;

  char* ws = (char*)d_ws;
  // persistent-within-call buffers
  bf16_t* wbT    = (bf16_t*)(ws + 0);            // [E][H][D] 33554432
  bf16_t* mrT    = (bf16_t*)(ws + 33554432);     // [M][H] 8388608
  bf16_t* memT   = (bf16_t*)(ws + 41943040);     // [H][M] 8388608
  float*  gate_t = (float*)(ws + 50331648);      // [E][B] 32768
  float*  connb  = (float*)(ws + 50364416);      // [E][H] 65536
  bf16_t* x_bf   = (bf16_t*)(ws + 50429952);     // 2097152 (ends 52527104)
  bf16_t* moe_bf = (bf16_t*)(ws + 52527104);     // 4194304 (ends 56721408)
  float*  h1p    = (float*)(ws + 56721408);      // [E][8][32] 8192 (ends 56729600)
  // aliases (regions dead by the time these are written)
  float*  logits = (float*)(ws + 0);             // [2][B][M] 16777216 (wbT dead)
  bf16_t* attn   = (bf16_t*)(ws + 16777216);     // 4194304 (ends 20971520)
  float*  readv  = (float*)(ws + 0);             // [2][B][H] 16777216 (logits dead)
  float*  moe    = out;                          // [B][H] f32 lives in d_out

  // 1. one-time conversions / transposes
  cvt_kernel<<<dim3(512), 256, 0, stream>>>(x, x_bf);
  transpose_all<<<dim3(32, 32, 10), 256, 0, stream>>>(expert_w, mem_rw, memory, wbT, mrT, memT);
  // 2. gate + conn
  gate_kernel<<<dim3(B_DIM), 256, 0, stream>>>(x, gate_w, gate_t);
  conn1_kernel<<<dim3(64), 256, 0, stream>>>(navg, conn_w1, h1p);
  conn2_kernel<<<dim3(64), 256, 0, stream>>>(h1p, conn_b1, conn_w2, conn_b2, nmask, connb);
  // 3. expert GEMM, all experts in registers, writes moe (f32, d_out) + moe_bf
  expert_gemm<<<dim3(256), 512, 0, stream>>>(x_bf, wbT, moe, moe_bf, gate_t, connb, expert_b);
  // 4. memory attention: split-K2 GEMMs -> partials, fused sums downstream
  gemm_sk2<<<dim3(256), 256, 0, stream>>>(moe_bf, mrT, logits);
  softmax_kernel<<<dim3(B_DIM), 256, 0, stream>>>(logits, mem_rb, attn);
  gemm_sk2<<<dim3(256), 256, 0, stream>>>(attn, memT, readv);
  // 5. blended activation (in-place on d_out)
  act_kernel<<<dim3((B_DIM * H_DIM) / (256 * 4)), 256, 0, stream>>>(readv, act_w, out);
}

// Round 7
// 139.993 us; speedup vs baseline: 2.4707x; 1.0489x over previous
//
#include <hip/hip_runtime.h>
#include <hip/hip_bf16.h>
#include <math.h>

typedef __bf16 bf16_t;
typedef __bf16 bf16x8 __attribute__((ext_vector_type(8)));
typedef float f32x4 __attribute__((ext_vector_type(4)));

#define B_DIM 1024
#define D_DIM 1024
#define H_DIM 2048
#define E_DIM 8
#define M_DIM 2048

typedef const __attribute__((address_space(1))) unsigned int as1_uint;
typedef __attribute__((address_space(3))) unsigned int as3_uint;

__device__ __forceinline__ void gl_lds16(const void* g, void* l) {
  __builtin_amdgcn_global_load_lds((as1_uint*)g, (as3_uint*)l, 16, 0, 0);
}

#define WAITV(n) asm volatile("s_waitcnt vmcnt(" #n ")" ::: "memory")

// ---------------- f32 -> bf16 convert (8 elems/thread) ----------------
__global__ __launch_bounds__(256) void cvt_kernel(const float* __restrict__ in,
                                                  bf16_t* __restrict__ out) {
  size_t i = ((size_t)blockIdx.x * 256 + threadIdx.x) * 8;
  float4 a = *(const float4*)&in[i];
  float4 b = *(const float4*)&in[i + 4];
  bf16x8 o;
  o[0] = (bf16_t)a.x; o[1] = (bf16_t)a.y; o[2] = (bf16_t)a.z; o[3] = (bf16_t)a.w;
  o[4] = (bf16_t)b.x; o[5] = (bf16_t)b.y; o[6] = (bf16_t)b.z; o[7] = (bf16_t)b.w;
  *(bf16x8*)&out[i] = o;
}

// ---------------- merged transpose + cvt: z<8 expert_w slab, z=8 mem_rw, z=9 memory --------
__global__ __launch_bounds__(256) void transpose_all(
    const float* __restrict__ ew, const float* __restrict__ mrw, const float* __restrict__ mem,
    bf16_t* __restrict__ wbT, bf16_t* __restrict__ mrT, bf16_t* __restrict__ memT) {
  __shared__ float tile[64][65];
  const int z = blockIdx.z;
  const float* in; bf16_t* out; int R, C;
  if (z < 8) {
    if (blockIdx.y >= 16) return;
    in = ew + (size_t)z * D_DIM * H_DIM; out = wbT + (size_t)z * D_DIM * H_DIM;
    R = D_DIM; C = H_DIM;
  } else if (z == 8) {
    in = mrw; out = mrT; R = H_DIM; C = M_DIM;
  } else {
    in = mem; out = memT; R = M_DIM; C = H_DIM;
  }
  int c0 = blockIdx.x * 64, r0 = blockIdx.y * 64;
  int t = threadIdx.x;
  int cq = (t & 15) * 4, rr = t >> 4;
#pragma unroll
  for (int i = 0; i < 4; ++i) {
    int r = rr + 16 * i;
    float4 v = *(const float4*)&in[(size_t)(r0 + r) * C + c0 + cq];
    tile[r][cq] = v.x; tile[r][cq + 1] = v.y; tile[r][cq + 2] = v.z; tile[r][cq + 3] = v.w;
  }
  __syncthreads();
  int r8 = (t & 7) * 8, cc = t >> 3;
#pragma unroll
  for (int i = 0; i < 2; ++i) {
    int c = cc + 32 * i;
    bf16x8 o;
#pragma unroll
    for (int j = 0; j < 8; ++j) o[j] = (bf16_t)tile[r8 + j][c];
    *(bf16x8*)&out[(size_t)(c0 + c) * R + r0 + r8] = o;
  }
}

// ---------------- gate: softmax(x @ gate_w) -> gate_t [E][B] f32 ----------------
__global__ __launch_bounds__(256) void gate_kernel(
    const float* __restrict__ x, const float* __restrict__ gw, float* __restrict__ gate_t) {
  __shared__ float red[256][8];
  int b = blockIdx.x, t = threadIdx.x;
  float acc[8] = {0.f, 0.f, 0.f, 0.f, 0.f, 0.f, 0.f, 0.f};
  for (int d = t; d < D_DIM; d += 256) {
    float xv = x[(size_t)b * D_DIM + d];
#pragma unroll
    for (int e = 0; e < 8; ++e) acc[e] += xv * gw[d * 8 + e];
  }
#pragma unroll
  for (int e = 0; e < 8; ++e) red[t][e] = acc[e];
  __syncthreads();
  for (int s = 128; s > 0; s >>= 1) {
    if (t < s) {
#pragma unroll
      for (int e = 0; e < 8; ++e) red[t][e] += red[t + s][e];
    }
    __syncthreads();
  }
  if (t == 0) {
    float m = red[0][0];
#pragma unroll
    for (int e = 1; e < 8; ++e) m = fmaxf(m, red[0][e]);
    float p[8], sum = 0.f;
#pragma unroll
    for (int e = 0; e < 8; ++e) { p[e] = expf(red[0][e] - m); sum += p[e]; }
    float inv = 1.f / sum;
#pragma unroll
    for (int e = 0; e < 8; ++e) gate_t[e * B_DIM + b] = p[e] * inv;
  }
}

// ---------------- conn part 1: per-(e,chunk) partial reduce -> h1p [E][8][32] ----------------
__global__ __launch_bounds__(256) void conn1_kernel(
    const float* __restrict__ avg, const float* __restrict__ w1, float* __restrict__ h1p) {
  __shared__ float red[256 * 32];
  int e = blockIdx.x >> 3, c = blockIdx.x & 7, t = threadIdx.x;
  int h = c * 256 + t;
  float av = avg[e * H_DIM + h];
  const float* w1p = &w1[((size_t)e * H_DIM + h) * 32];
#pragma unroll
  for (int k = 0; k < 32; ++k) red[t * 32 + k] = av * w1p[k];
  __syncthreads();
  for (int s = 128; s > 0; s >>= 1) {
    if (t < s) {
#pragma unroll
      for (int k = 0; k < 32; ++k) red[t * 32 + k] += red[(t + s) * 32 + k];
    }
    __syncthreads();
  }
  if (t < 32) h1p[(e * 8 + c) * 32 + t] = red[t];
}

// ---------------- conn part 2: sum partials, relu, sigmoid map -> conn [E][H] ----------------
__global__ __launch_bounds__(256) void conn2_kernel(
    const float* __restrict__ h1p, const float* __restrict__ b1,
    const float* __restrict__ w2, const float* __restrict__ b2,
    const float* __restrict__ mask, float* __restrict__ conn) {
  __shared__ float h1[32];
  int e = blockIdx.x >> 3, c = blockIdx.x & 7, t = threadIdx.x;
  if (t < 32) {
    float s = 0.f;
#pragma unroll
    for (int c2 = 0; c2 < 8; ++c2) s += h1p[(e * 8 + c2) * 32 + t];
    h1[t] = fmaxf(s + b1[e * 32 + t], 0.f);
  }
  __syncthreads();
  int h = c * 256 + t;
  float s = b2[e * H_DIM + h];
#pragma unroll
  for (int k = 0; k < 32; ++k) s += h1[k] * w2[((size_t)e * 32 + k) * H_DIM + h];
  conn[e * H_DIM + h] = (1.f / (1.f + expf(-s))) * mask[e * H_DIM + h];
}

// ---------------- expert GEMM: 128x64 tile, 8 experts in registers, ds-read-ahead phases ----
// Phase p=(kt,e): {ds_read breg(e+1) | stage slot e+5 | counted vmcnt | barrier | 8 MFMA(e)}.
// Ledger (queue-simulated): B load issued at flat phase p is ds_read at top of p+4, so it must
// retire at p+3's wait. Steady state: e<4 -> vmcnt(5) [3B + A-pair left], e>=4 -> vmcnt(3).
// Prologue: 7 issued (A*2,B0..B4); retire A*2+B0+B1 -> vmcnt(3). Tail kt=15: 3,3,3,2,1,0,0,0.
__global__ __launch_bounds__(512, 2) void expert_gemm(
    const bf16_t* __restrict__ A, const bf16_t* __restrict__ Bt,
    float* __restrict__ moe, bf16_t* __restrict__ moebf,
    const float* __restrict__ gate_t, const float* __restrict__ conn,
    const float* __restrict__ ebias) {
  __shared__ bf16_t As[2][128 * 64];   // 32 KB
  __shared__ bf16_t Bs[8][64 * 64];    // 64 KB

  const int wid = (blockIdx.x & 7) * 32 + (blockIdx.x >> 3);
  const int b0 = (wid & 7) * 128;
  const int n0 = (wid >> 3) * 64;

  const int t = threadIdx.x;
  const int lane = t & 63, wave = t >> 6;
  const int wmh = wave >> 2, wnq = wave & 3;
  const int lr = lane & 15, lk = (lane >> 4) * 8;
  const int csw = (lr & 7) << 3;
  const int srow = lane >> 3;
  const int scol = ((lane & 7) ^ srow) << 3;
  const size_t EB = (size_t)H_DIM * D_DIM;

  const bf16_t* Asrc = A + (size_t)(b0 + wave * 16 + srow) * D_DIM + scol;
  const bf16_t* Bsrc = Bt + (size_t)(n0 + wave * 8 + srow) * D_DIM + scol;

  auto stageA = [&](int buf, int kt) {
    gl_lds16(Asrc + (size_t)kt * 64, &As[buf][(wave * 16) * 64]);
    gl_lds16(Asrc + 8 * D_DIM + (size_t)kt * 64, &As[buf][(wave * 16 + 8) * 64]);
  };
  auto stageB = [&](int slot, int e, int kt) {
    gl_lds16(Bsrc + (size_t)e * EB + (size_t)kt * 64, &Bs[slot][(wave * 8) * 64]);
  };
  auto readB = [&](int slot, bf16x8& r0, bf16x8& r1) {
    const bf16_t* Bb = &Bs[slot][0];
    r0 = *(const bf16x8*)&Bb[(wnq * 16 + lr) * 64 + (lk ^ csw)];
    r1 = *(const bf16x8*)&Bb[(wnq * 16 + lr) * 64 + ((32 + lk) ^ csw)];
  };

  f32x4 acc[8][4];
#pragma unroll
  for (int e = 0; e < 8; ++e)
#pragma unroll
    for (int mf = 0; mf < 4; ++mf) acc[e][mf] = (f32x4){0.f, 0.f, 0.f, 0.f};

  // prologue: A(0), B slots 0..4 of kt0; retire A,B0,B1 (4 of 7) before reading slots 0/1
  stageA(0, 0);
#pragma unroll
  for (int s = 0; s < 5; ++s) stageB(s, s, 0);
  WAITV(3);
  __builtin_amdgcn_s_barrier();
  __builtin_amdgcn_sched_barrier(0);
  bf16x8 bc0, bc1, bn0, bn1;
  readB(0, bc0, bc1);

  for (int kt = 0; kt < 16; ++kt) {
    const int ab = kt & 1;
    const bool last = (kt == 15);
    bf16x8 af[2][4];
#pragma unroll
    for (int e = 0; e < 8; ++e) {
      // 1. ds_read breg for phase e+1 (slot guaranteed by previous phase's wait+barrier)
      if (!(last && e == 7)) readB((e + 1) & 7, bn0, bn1);
      // 2. issue stage for phase e+5
      if (e < 3) {
        stageB((e + 5) & 7, e + 5, kt);
        if (e == 0 && !last) stageA(ab ^ 1, kt + 1);
      } else if (!last) {
        stageB((e + 5) & 7, e - 3, kt + 1);
      }
      // 3. counted vmcnt: retire the B-load issued 3 phases ago (read next phase)
      if (!last) {
        if (e < 4) { WAITV(5); } else { WAITV(3); }
      } else {
        if (e < 3)       { WAITV(3); }
        else if (e == 3) { WAITV(2); }
        else if (e == 4) { WAITV(1); }
        else             { WAITV(0); }
      }
      // 4. barrier (pinned: nothing crosses)
      __builtin_amdgcn_s_barrier();
      __builtin_amdgcn_sched_barrier(0);
      // 5. A fragments once per kt (A(kt) retired + barrier'd)
      if (e == 0) {
#pragma unroll
        for (int kk = 0; kk < 2; ++kk)
#pragma unroll
          for (int mf = 0; mf < 4; ++mf)
            af[kk][mf] = *(const bf16x8*)&As[ab][(wmh * 64 + mf * 16 + lr) * 64 +
                                                ((kk * 32 + lk) ^ csw)];
      }
      // 6. MFMA on fragments read LAST phase
      __builtin_amdgcn_s_setprio(1);
#pragma unroll
      for (int mf = 0; mf < 4; ++mf) {
        acc[e][mf] = __builtin_amdgcn_mfma_f32_16x16x32_bf16(af[0][mf], bc0, acc[e][mf], 0, 0, 0);
        acc[e][mf] = __builtin_amdgcn_mfma_f32_16x16x32_bf16(af[1][mf], bc1, acc[e][mf], 0, 0, 0);
      }
      __builtin_amdgcn_s_setprio(0);
      bc0 = bn0; bc1 = bn1;
    }
  }

  // epilogue: per-expert gate/conn/bias/relu, register sum over e, single store
  const int r4 = (lane >> 4) * 4;
  const int gcol = n0 + wnq * 16 + lr;
  const int growb = b0 + wmh * 64;
  f32x4 sum[4];
#pragma unroll
  for (int mf = 0; mf < 4; ++mf) sum[mf] = (f32x4){0.f, 0.f, 0.f, 0.f};
#pragma unroll
  for (int e = 0; e < 8; ++e) {
    const float cm = conn[e * H_DIM + gcol];
    const float bb = ebias[e * H_DIM + gcol];
#pragma unroll
    for (int mf = 0; mf < 4; ++mf) {
      const float4 g4 = *(const float4*)&gate_t[e * B_DIM + growb + mf * 16 + r4];
      sum[mf][0] += fmaxf((acc[e][mf][0] + bb) * cm, 0.f) * g4.x;
      sum[mf][1] += fmaxf((acc[e][mf][1] + bb) * cm, 0.f) * g4.y;
      sum[mf][2] += fmaxf((acc[e][mf][2] + bb) * cm, 0.f) * g4.z;
      sum[mf][3] += fmaxf((acc[e][mf][3] + bb) * cm, 0.f) * g4.w;
    }
  }
#pragma unroll
  for (int mf = 0; mf < 4; ++mf)
#pragma unroll
    for (int j = 0; j < 4; ++j) {
      const int grow = growb + mf * 16 + r4 + j;
      moe[(size_t)grow * H_DIM + gcol] = sum[mf][j];
      moebf[(size_t)grow * H_DIM + gcol] = (bf16_t)sum[mf][j];
    }
}

// ---------------- stage-2 GEMM: 128x128 tile, 512 thr / 8 waves (2x4), split-K x2 ----------
__global__ __launch_bounds__(512, 2) void gemm_sk2(
    const bf16_t* __restrict__ A, const bf16_t* __restrict__ Bt, float* __restrict__ C) {
  __shared__ bf16_t As[2][128 * 64];
  __shared__ bf16_t Bs[2][128 * 64];

  const int wid = (blockIdx.x & 7) * 32 + (blockIdx.x >> 3);
  const int ez = wid >> 7;          // split-K half 0..1
  const int rem = wid & 127;
  const int b0 = (rem & 7) * 128;
  const int n0 = (rem >> 3) * 128;
  const int kbase = ez << 10;       // *1024

  const int t = threadIdx.x;
  const int lane = t & 63, wave = t >> 6;
  const int wm = wave >> 2, wn = wave & 3;   // 2 x 4
  const int lr = lane & 15, lk = (lane >> 4) * 8;
  const int csw = (lr & 7) << 3;
  const int srow = lane >> 3;
  const int scol = ((lane & 7) ^ srow) << 3;

  const bf16_t* Arow = A + (size_t)(b0 + srow) * 2048 + kbase + scol;
  const bf16_t* Brow = Bt + (size_t)(n0 + srow) * 2048 + kbase + scol;

  const f32x4 zv = {0.f, 0.f, 0.f, 0.f};
  f32x4 acc[4][2];
#pragma unroll
  for (int mf = 0; mf < 4; ++mf)
#pragma unroll
    for (int nf = 0; nf < 2; ++nf) acc[mf][nf] = zv;

  auto STAGE = [&](int bsel, int kt) {
    const int ko = kt << 6;
#pragma unroll
    for (int i = 0; i < 2; ++i) {
      int rb = i * 64 + wave * 8;
      gl_lds16(Arow + (size_t)rb * 2048 + ko, &As[bsel][rb * 64]);
      gl_lds16(Brow + (size_t)rb * 2048 + ko, &Bs[bsel][rb * 64]);
    }
  };

  auto COMPUTE = [&](int bsel) {
    bf16x8 bfr[2][2];
#pragma unroll
    for (int kk = 0; kk < 2; ++kk)
#pragma unroll
      for (int nf = 0; nf < 2; ++nf)
        bfr[kk][nf] = *(const bf16x8*)&Bs[bsel][(wn * 32 + nf * 16 + lr) * 64 + ((kk * 32 + lk) ^ csw)];
    __builtin_amdgcn_s_setprio(1);
#pragma unroll
    for (int mf = 0; mf < 4; ++mf) {
      bf16x8 a0 = *(const bf16x8*)&As[bsel][(wm * 64 + mf * 16 + lr) * 64 + (lk ^ csw)];
      bf16x8 a1 = *(const bf16x8*)&As[bsel][(wm * 64 + mf * 16 + lr) * 64 + ((32 + lk) ^ csw)];
#pragma unroll
      for (int nf = 0; nf < 2; ++nf)
        acc[mf][nf] = __builtin_amdgcn_mfma_f32_16x16x32_bf16(a0, bfr[0][nf], acc[mf][nf], 0, 0, 0);
#pragma unroll
      for (int nf = 0; nf < 2; ++nf)
        acc[mf][nf] = __builtin_amdgcn_mfma_f32_16x16x32_bf16(a1, bfr[1][nf], acc[mf][nf], 0, 0, 0);
    }
    __builtin_amdgcn_s_setprio(0);
  };

  STAGE(0, 0);
  __syncthreads();
  for (int kt = 0; kt < 15; ++kt) {
    STAGE((kt + 1) & 1, kt + 1);
    COMPUTE(kt & 1);
    __syncthreads();
  }
  COMPUTE(1);

  const int r4 = (lane >> 4) * 4;
#pragma unroll
  for (int mf = 0; mf < 4; ++mf) {
#pragma unroll
    for (int nf = 0; nf < 2; ++nf) {
      int gcol = n0 + wn * 32 + nf * 16 + lr;
#pragma unroll
      for (int j = 0; j < 4; ++j) {
        int grow = b0 + wm * 64 + mf * 16 + r4 + j;
        C[((size_t)ez * B_DIM + grow) * 2048 + gcol] = acc[mf][nf][j];
      }
    }
  }
}

// ---------------- softmax over M: sum 2 split-K partials + bias -> bf16 attn ----------------
__global__ __launch_bounds__(256) void softmax_kernel(
    const float* __restrict__ lg, const float* __restrict__ bias, bf16_t* __restrict__ attn) {
  const size_t P = (size_t)B_DIM * M_DIM;
  int b = blockIdx.x, t = threadIdx.x;
  int lane = t & 63, wave = t >> 6;
  __shared__ float rmax[4], rsum[4];
  float v[8];
  float m = -1e30f;
#pragma unroll
  for (int i = 0; i < 8; ++i) {
    size_t idx = (size_t)b * M_DIM + i * 256 + t;
    v[i] = lg[idx] + lg[P + idx] + bias[i * 256 + t];
    m = fmaxf(m, v[i]);
  }
#pragma unroll
  for (int off = 32; off >= 1; off >>= 1) m = fmaxf(m, __shfl_xor(m, off));
  if (lane == 0) rmax[wave] = m;
  __syncthreads();
  m = fmaxf(fmaxf(rmax[0], rmax[1]), fmaxf(rmax[2], rmax[3]));
  float s = 0.f;
#pragma unroll
  for (int i = 0; i < 8; ++i) {
    v[i] = __expf(v[i] - m);
    s += v[i];
  }
#pragma unroll
  for (int off = 32; off >= 1; off >>= 1) s += __shfl_xor(s, off);
  if (lane == 0) rsum[wave] = s;
  __syncthreads();
  s = rsum[0] + rsum[1] + rsum[2] + rsum[3];
  float inv = 1.f / s;
#pragma unroll
  for (int i = 0; i < 8; ++i) attn[(size_t)b * M_DIM + i * 256 + t] = (bf16_t)(v[i] * inv);
}

// ---------------- final blended activation: out = act(out + sum of 2 readv partials) --------
__global__ __launch_bounds__(256) void act_kernel(
    const float* __restrict__ rdv, const float* __restrict__ aw, float* __restrict__ out) {
  const size_t P = (size_t)B_DIM * H_DIM;
  int i = blockIdx.x * 256 + threadIdx.x;
  float w[9], m = -1e30f;
#pragma unroll
  for (int j = 0; j < 9; ++j) { w[j] = aw[j]; m = fmaxf(m, w[j]); }
  float p[9], s = 0.f;
#pragma unroll
  for (int j = 0; j < 9; ++j) { p[j] = expf(w[j] - m); s += p[j]; }
  float inv = 1.f / s;
#pragma unroll
  for (int j = 0; j < 9; ++j) p[j] *= inv;
  float4 mv = ((const float4*)out)[i];
  float4 r0 = ((const float4*)rdv)[i];
  float4 r1 = ((const float4*)(rdv + P))[i];
  float xs[4] = {mv.x + r0.x + r1.x, mv.y + r0.y + r1.y,
                 mv.z + r0.z + r1.z, mv.w + r0.w + r1.w};
  float os[4];
#pragma unroll
  for (int q = 0; q < 4; ++q) {
    float xv = xs[q];
    float enx = expf(-xv);
    float ex = expf(xv);
    float sig = 1.f / (1.f + enx);
    float em1 = expm1f(xv);
    float th = tanhf(xv);
    float rl = fmaxf(xv, 0.f);
    float si = xv * sig;
    float ge = 0.5f * xv * (1.f + erff(xv * 0.70710678118654752f));
    float se = 1.0507009873554805f * (xv > 0.f ? xv : 1.6732632423543772f * em1);
    float el = xv > 0.f ? xv : em1;
    float sp = log1pf(ex);
    float mi = xv * tanhf(sp);
    os[q] = p[0] * sig + p[1] * el + p[2] * th + p[3] * rl + p[4] * si + p[5] * ge + p[6] * se + p[7] * mi;
  }
  ((float4*)out)[i] = make_float4(os[0], os[1], os[2], os[3]);
}

extern "C" void kernel_launch(void* const* d_in, const int* in_sizes, int n_in,
                              void* d_out, int out_size, void* d_ws, size_t ws_size,
                              hipStream_t stream) {
  const float* x        = (const float*)d_in[0];
  const float* gate_w   = (const float*)d_in[1];
  const float* expert_w = (const float*)d_in[2];
  const float* expert_b = (const float*)d_in[3];
  const float* conn_w1  = (const float*)d_in[4];
  const float* conn_b1  = (const float*)d_in[5];
  const float* conn_w2  = (const float*)d_in[6];
  const float* conn_b2  = (const float*)d_in[7];
  const float* navg     = (const float*)d_in[8];
  const float* nmask    = (const float*)d_in[9];
  const float* mem_rw   = (const float*)d_in[10];
  const float* mem_rb   = (const float*)d_in[11];
  const float* memory   = (const float*)d_in[12];
  const float* act_w    = (const float*)d_in[13];
  float* out = (float*)d_out;

  char* ws = (char*)d_ws;
  // persistent-within-call buffers
  bf16_t* wbT    = (bf16_t*)(ws + 0);            // [E][H][D] 33554432
  bf16_t* mrT    = (bf16_t*)(ws + 33554432);     // [M][H] 8388608
  bf16_t* memT   = (bf16_t*)(ws + 41943040);     // [H][M] 8388608
  float*  gate_t = (float*)(ws + 50331648);      // [E][B] 32768
  float*  connb  = (float*)(ws + 50364416);      // [E][H] 65536
  bf16_t* x_bf   = (bf16_t*)(ws + 50429952);     // 2097152 (ends 52527104)
  bf16_t* moe_bf = (bf16_t*)(ws + 52527104);     // 4194304 (ends 56721408)
  float*  h1p    = (float*)(ws + 56721408);      // [E][8][32] 8192 (ends 56729600)
  // aliases (regions dead by the time these are written)
  float*  logits = (float*)(ws + 0);             // [2][B][M] 16777216 (wbT dead)
  bf16_t* attn   = (bf16_t*)(ws + 16777216);     // 4194304 (ends 20971520)
  float*  readv  = (float*)(ws + 0);             // [2][B][H] 16777216 (logits dead)
  float*  moe    = out;                          // [B][H] f32 lives in d_out

  // 1. one-time conversions / transposes
  cvt_kernel<<<dim3(512), 256, 0, stream>>>(x, x_bf);
  transpose_all<<<dim3(32, 32, 10), 256, 0, stream>>>(expert_w, mem_rw, memory, wbT, mrT, memT);
  // 2. gate + conn
  gate_kernel<<<dim3(B_DIM), 256, 0, stream>>>(x, gate_w, gate_t);
  conn1_kernel<<<dim3(64), 256, 0, stream>>>(navg, conn_w1, h1p);
  conn2_kernel<<<dim3(64), 256, 0, stream>>>(h1p, conn_b1, conn_w2, conn_b2, nmask, connb);
  // 3. expert GEMM, all experts in registers, writes moe (f32, d_out) + moe_bf
  expert_gemm<<<dim3(256), 512, 0, stream>>>(x_bf, wbT, moe, moe_bf, gate_t, connb, expert_b);
  // 4. memory attention: split-K2 GEMMs -> partials, fused sums downstream
  gemm_sk2<<<dim3(256), 512, 0, stream>>>(moe_bf, mrT, logits);
  softmax_kernel<<<dim3(B_DIM), 256, 0, stream>>>(logits, mem_rb, attn);
  gemm_sk2<<<dim3(256), 512, 0, stream>>>(attn, memT, readv);
  // 5. blended activation (in-place on d_out)
  act_kernel<<<dim3((B_DIM * H_DIM) / (256 * 4)), 256, 0, stream>>>(readv, act_w, out);
}